// Round 2
// baseline (437.947 us; speedup 1.0000x reference)
//
#include <hip/hip_runtime.h>
#include <hip/hip_bf16.h>

// ---- problem constants ----
#define S_    4096
#define D_    1024
#define H_    8
#define DH_   64
#define ETA_  4
#define R_    8
#define E_    256
#define NC_   128          // scan chunks
#define LC_   (S_/NC_)     // 32 steps per chunk
#define N1_   2688         // padded N for GEMM1 (21*128); cols: [0,2560)=kqvbg, [2560,2656)=p, rest zero
#define NKQV_ 2560
#define NP_   96
#define PIF   3.14159265358979323846

typedef unsigned short u16;
typedef short v8s __attribute__((ext_vector_type(8)));
typedef float v4f __attribute__((ext_vector_type(4)));

__device__ __forceinline__ u16 f2bf(float f) {
    unsigned u = __builtin_bit_cast(unsigned, f);
    return (u16)((u + 0x7FFFu + ((u >> 16) & 1u)) >> 16);
}
__device__ __forceinline__ float bf2f(u16 h) {
    return __builtin_bit_cast(float, (unsigned)h << 16);
}
__device__ __forceinline__ float sigm(float x) { return 1.f / (1.f + expf(-x)); }

// ---- prep: fp32 -> bf16 hi/lo split (8 elems/thread) ----
__global__ __launch_bounds__(256) void cvt8_split(const float* __restrict__ x,
                                                  u16* __restrict__ oh, u16* __restrict__ ol, int n8) {
    int i = blockIdx.x * 256 + threadIdx.x;
    if (i >= n8) return;
    const float4* xp = (const float4*)x;
    float4 a = xp[2 * i], b = xp[2 * i + 1];
    float v[8] = {a.x, a.y, a.z, a.w, b.x, b.y, b.z, b.w};
    unsigned hh[8], ll[8];
    #pragma unroll
    for (int j = 0; j < 8; ++j) {
        u16 h = f2bf(v[j]);
        hh[j] = h;
        ll[j] = f2bf(v[j] - bf2f(h));
    }
    uint4 rh, rl;
    rh.x = hh[0] | (hh[1] << 16); rh.y = hh[2] | (hh[3] << 16);
    rh.z = hh[4] | (hh[5] << 16); rh.w = hh[6] | (hh[7] << 16);
    rl.x = ll[0] | (ll[1] << 16); rl.y = ll[2] | (ll[3] << 16);
    rl.z = ll[4] | (ll[5] << 16); rl.w = ll[6] | (ll[7] << 16);
    ((uint4*)oh)[i] = rh;
    ((uint4*)ol)[i] = rl;
}

// ---- prep: combined B matrix [W_kqv | W_p | 0] (1024 x 2688) bf16 hi/lo + bias buffer ----
__global__ __launch_bounds__(256) void prep_b1_split(const float* __restrict__ Wk, const float* __restrict__ Wp,
                                                     const float* __restrict__ bk, const float* __restrict__ bp,
                                                     u16* __restrict__ BoH, u16* __restrict__ BoL,
                                                     float* __restrict__ biasb) {
    int idx = blockIdx.x * 256 + threadIdx.x;
    if (idx >= D_ * N1_) return;
    int k = idx / N1_, n = idx % N1_;
    float v = 0.f;
    if (n < NKQV_) v = Wk[(size_t)k * NKQV_ + n];
    else if (n < NKQV_ + NP_) v = Wp[(size_t)k * NP_ + (n - NKQV_)];
    u16 h = f2bf(v);
    BoH[idx] = h;
    BoL[idx] = f2bf(v - bf2f(h));
    if (k == 0) {
        float bv = 0.f;
        if (n < NKQV_) bv = bk[n];
        else if (n < NKQV_ + NP_) bv = bp[n - NKQV_];
        biasb[n] = bv;
    }
}

// ---- prep: oscillator table OC[t][r] = cos((tick0+t+1)*omega_r), replicating fp32 reference math ----
__global__ __launch_bounds__(256) void prep_oc(const float* __restrict__ tick, float* __restrict__ OC) {
    int idx = blockIdx.x * 256 + threadIdx.x;
    if (idx >= S_ * R_) return;
    int t = idx / R_, r = idx % R_;
    float start = (float)(-PIF), stop = (float)PIF;
    float step = __fdiv_rn(__fsub_rn(stop, start), 7.0f);
    float om = __fadd_rn(start, __fmul_rn((float)r, step));
    float tk = __fadd_rn(tick[0], (float)(t + 1));
    OC[idx] = cosf(__fmul_rn(tk, om));
}

// ---- split-bf16 MFMA GEMM: Y = (Ah+Al)(Bh+Bl) + bias, dropping lo*lo -> ~fp32 accurate ----
// 128x128 tile, 4 waves, 3 MFMA per fragment pair.
__global__ __launch_bounds__(256) void gemm_bf16x3(const u16* __restrict__ Ah, const u16* __restrict__ Al, int lda,
                                                   const u16* __restrict__ Bh, const u16* __restrict__ Bl, int ldb,
                                                   const float* __restrict__ bias,
                                                   float* __restrict__ Yo, int ldy, int Kdim) {
    __shared__ __align__(16) u16 AsH[128][56], AsL[128][56];   // row stride 112B
    __shared__ __align__(16) u16 BsH[128][56], BsL[128][56];   // transposed: Bs[n][k]
    const int tid = threadIdx.x;
    const int lane = tid & 63;
    const int w = tid >> 6;
    const int mw = (w >> 1) * 64, nw = (w & 1) * 64;
    const int m0 = blockIdx.y * 128, n0 = blockIdx.x * 128;
    const int l15 = lane & 15, lk = (lane >> 4) * 8;
    const int ar = tid >> 1, ac = (tid & 1) * 16;
    const int bk2 = (tid & 15) * 2, bn8 = (tid >> 4) * 8;
    v4f acc[4][4] = {};
    for (int k0 = 0; k0 < Kdim; k0 += 32) {
        const u16* Aph = Ah + (size_t)(m0 + ar) * lda + k0 + ac;
        const u16* Apl = Al + (size_t)(m0 + ar) * lda + k0 + ac;
        uint4 ah0 = *(const uint4*)Aph, ah1 = *(const uint4*)(Aph + 8);
        uint4 al0 = *(const uint4*)Apl, al1 = *(const uint4*)(Apl + 8);
        size_t bo0 = (size_t)(k0 + bk2) * ldb + n0 + bn8;
        size_t bo1 = bo0 + ldb;
        uint4 bh0 = *(const uint4*)(Bh + bo0), bh1 = *(const uint4*)(Bh + bo1);
        uint4 bl0 = *(const uint4*)(Bl + bo0), bl1 = *(const uint4*)(Bl + bo1);
        __syncthreads();
        *(uint4*)&AsH[ar][ac] = ah0; *(uint4*)&AsH[ar][ac + 8] = ah1;
        *(uint4*)&AsL[ar][ac] = al0; *(uint4*)&AsL[ar][ac + 8] = al1;
        union { uint4 v; u16 s[8]; } th0, th1, tl0, tl1;
        th0.v = bh0; th1.v = bh1; tl0.v = bl0; tl1.v = bl1;
        #pragma unroll
        for (int i = 0; i < 8; ++i) {
            *(unsigned*)&BsH[bn8 + i][bk2] = (unsigned)th0.s[i] | ((unsigned)th1.s[i] << 16);
            *(unsigned*)&BsL[bn8 + i][bk2] = (unsigned)tl0.s[i] | ((unsigned)tl1.s[i] << 16);
        }
        __syncthreads();
        v8s afh[4], afl[4], bfh[4], bfl[4];
        #pragma unroll
        for (int f = 0; f < 4; ++f) {
            afh[f] = *(const v8s*)&AsH[mw + f * 16 + l15][lk];
            afl[f] = *(const v8s*)&AsL[mw + f * 16 + l15][lk];
            bfh[f] = *(const v8s*)&BsH[nw + f * 16 + l15][lk];
            bfl[f] = *(const v8s*)&BsL[nw + f * 16 + l15][lk];
        }
        #pragma unroll
        for (int i = 0; i < 4; ++i)
            #pragma unroll
            for (int j = 0; j < 4; ++j) {
                acc[i][j] = __builtin_amdgcn_mfma_f32_16x16x32_bf16(afh[i], bfh[j], acc[i][j], 0, 0, 0);
                acc[i][j] = __builtin_amdgcn_mfma_f32_16x16x32_bf16(afl[i], bfh[j], acc[i][j], 0, 0, 0);
                acc[i][j] = __builtin_amdgcn_mfma_f32_16x16x32_bf16(afh[i], bfl[j], acc[i][j], 0, 0, 0);
            }
    }
    #pragma unroll
    for (int i = 0; i < 4; ++i) {
        int row0 = m0 + mw + i * 16 + (lane >> 4) * 4;   // C/D: col=lane&15, row=(lane>>4)*4+reg (m89)
        #pragma unroll
        for (int j = 0; j < 4; ++j) {
            int col = n0 + nw + j * 16 + l15;
            float bv = bias ? bias[col] : 0.f;
            #pragma unroll
            for (int rg = 0; rg < 4; ++rg)
                Yo[(size_t)(row0 + rg) * ldy + col] = acc[i][j][rg] + bv;
        }
    }
}

// ---- scan phase 1: per (chunk,head) local scan from zero + decay products ----
// CL record (49 vectors of 64 floats): [0,32)=kc[r*4+e], [32,40)=vc[r], [40,44)=sc[e], [44,48)=Pg[e], 48=Pb
__global__ __launch_bounds__(64) void scan_p1(const float* __restrict__ Y1, const float* __restrict__ OC,
                                              const int* __restrict__ term, float* __restrict__ CL) {
    const int b = blockIdx.x, c = b / H_, h = b % H_, lane = threadIdx.x;
    float kc[R_][ETA_] = {}, vc[R_] = {}, sc[ETA_] = {};
    float Pg[ETA_] = {1.f, 1.f, 1.f, 1.f}, Pb = 1.f;
    for (int t = c * LC_; t < c * LC_ + LC_; ++t) {
        const float* row = Y1 + (size_t)t * N1_;
        const float* bh = row + h * 320;
        float kk = bh[lane], vv = bh[128 + lane], bb = bh[192 + lane], gg = bh[256 + lane];
        const float* pp = row + NKQV_ + h * 12;
        float nt = 1.f - (float)term[t];
        float sb = sigm(bb), sg = sigm(gg);
        float rk = fmaxf(kk, 0.f);
        float vals = vv * sb, dbv = (1.f - sb) * nt;
        float occ[R_];
        #pragma unroll
        for (int r = 0; r < R_; ++r) occ[r] = OC[t * R_ + r];
        #pragma unroll
        for (int e = 0; e < ETA_; ++e) {
            float gam = sg * sigm(pp[8 + e]);
            float kg = rk * fmaxf(pp[e], 0.f) * gam;
            float dgv = (1.f - gam) * nt;
            sc[e] = dgv * sc[e] + kg;
            Pg[e] *= dgv;
            #pragma unroll
            for (int r = 0; r < R_; ++r) kc[r][e] = dgv * kc[r][e] + kg * occ[r];
        }
        Pb *= dbv;
        #pragma unroll
        for (int r = 0; r < R_; ++r) vc[r] = dbv * vc[r] + vals * occ[r];
    }
    float* out = CL + (size_t)b * 49 * 64;
    #pragma unroll
    for (int r = 0; r < R_; ++r)
        #pragma unroll
        for (int e = 0; e < ETA_; ++e) out[(r * 4 + e) * 64 + lane] = kc[r][e];
    #pragma unroll
    for (int r = 0; r < R_; ++r) out[(32 + r) * 64 + lane] = vc[r];
    #pragma unroll
    for (int e = 0; e < ETA_; ++e) out[(40 + e) * 64 + lane] = sc[e];
    #pragma unroll
    for (int e = 0; e < ETA_; ++e) out[(44 + e) * 64 + lane] = Pg[e];
    out[48 * 64 + lane] = Pb;
}

// ---- scan phase 2: sequential chunk-combine per head; writes carry-in per chunk ----
__global__ __launch_bounds__(64) void scan_seq(const float* __restrict__ CL, float* __restrict__ CI,
                                               const float* __restrict__ TK, const float* __restrict__ TV,
                                               const float* __restrict__ SP) {
    const int h = blockIdx.x, lane = threadIdx.x;
    float kc[R_][ETA_], vc[R_], sc[ETA_];
    #pragma unroll
    for (int r = 0; r < R_; ++r)
        #pragma unroll
        for (int e = 0; e < ETA_; ++e) kc[r][e] = TK[((size_t)r * H_ + h) * E_ + lane * 4 + e];
    #pragma unroll
    for (int r = 0; r < R_; ++r) vc[r] = TV[((size_t)r * H_ + h) * DH_ + lane];
    #pragma unroll
    for (int e = 0; e < ETA_; ++e) sc[e] = SP[(size_t)h * E_ + lane * 4 + e];
    for (int c = 0; c < NC_; ++c) {
        float* ci = CI + (size_t)(c * H_ + h) * 44 * 64;
        #pragma unroll
        for (int r = 0; r < R_; ++r)
            #pragma unroll
            for (int e = 0; e < ETA_; ++e) ci[(r * 4 + e) * 64 + lane] = kc[r][e];
        #pragma unroll
        for (int r = 0; r < R_; ++r) ci[(32 + r) * 64 + lane] = vc[r];
        #pragma unroll
        for (int e = 0; e < ETA_; ++e) ci[(40 + e) * 64 + lane] = sc[e];
        const float* cl = CL + (size_t)(c * H_ + h) * 49 * 64;
        float Pg[ETA_], Pb = cl[48 * 64 + lane];
        #pragma unroll
        for (int e = 0; e < ETA_; ++e) Pg[e] = cl[(44 + e) * 64 + lane];
        #pragma unroll
        for (int r = 0; r < R_; ++r)
            #pragma unroll
            for (int e = 0; e < ETA_; ++e) kc[r][e] = Pg[e] * kc[r][e] + cl[(r * 4 + e) * 64 + lane];
        #pragma unroll
        for (int r = 0; r < R_; ++r) vc[r] = Pb * vc[r] + cl[(32 + r) * 64 + lane];
        #pragma unroll
        for (int e = 0; e < ETA_; ++e) sc[e] = Pg[e] * sc[e] + cl[(40 + e) * 64 + lane];
    }
}

// ---- scan phase 3: re-scan with carry-in, emit attn (bf16 hi/lo, S x 512) ----
__global__ __launch_bounds__(64) void scan_p3(const float* __restrict__ Y1, const float* __restrict__ OC,
                                              const int* __restrict__ term, const float* __restrict__ CI,
                                              u16* __restrict__ attnH, u16* __restrict__ attnL) {
    const int b = blockIdx.x, c = b / H_, h = b % H_, lane = threadIdx.x;
    float kc[R_][ETA_], vc[R_], sc[ETA_];
    const float* ci = CI + (size_t)b * 44 * 64;
    #pragma unroll
    for (int r = 0; r < R_; ++r)
        #pragma unroll
        for (int e = 0; e < ETA_; ++e) kc[r][e] = ci[(r * 4 + e) * 64 + lane];
    #pragma unroll
    for (int r = 0; r < R_; ++r) vc[r] = ci[(32 + r) * 64 + lane];
    #pragma unroll
    for (int e = 0; e < ETA_; ++e) sc[e] = ci[(40 + e) * 64 + lane];
    for (int t = c * LC_; t < c * LC_ + LC_; ++t) {
        const float* row = Y1 + (size_t)t * N1_;
        const float* bh = row + h * 320;
        float kk = bh[lane], qq = bh[64 + lane], vv = bh[128 + lane], bb = bh[192 + lane], gg = bh[256 + lane];
        const float* pp = row + NKQV_ + h * 12;
        float nt = 1.f - (float)term[t];
        float sb = sigm(bb), sg = sigm(gg);
        float rk = fmaxf(kk, 0.f), rq = fmaxf(qq, 0.f);
        float vals = vv * sb, dbv = (1.f - sb) * nt;
        float occ[R_];
        #pragma unroll
        for (int r = 0; r < R_; ++r) occ[r] = OC[t * R_ + r];
        float qe[ETA_];
        #pragma unroll
        for (int e = 0; e < ETA_; ++e) {
            float gam = sg * sigm(pp[8 + e]);
            float kg = rk * fmaxf(pp[e], 0.f) * gam;
            float dgv = (1.f - gam) * nt;
            qe[e] = rq * fmaxf(pp[4 + e], 0.f);
            sc[e] = dgv * sc[e] + kg;
            #pragma unroll
            for (int r = 0; r < R_; ++r) kc[r][e] = dgv * kc[r][e] + kg * occ[r];
        }
        #pragma unroll
        for (int r = 0; r < R_; ++r) vc[r] = dbv * vc[r] + vals * occ[r];
        float kdq[R_], nrm = 0.f;
        #pragma unroll
        for (int r = 0; r < R_; ++r) {
            float s = 0.f;
            #pragma unroll
            for (int e = 0; e < ETA_; ++e) s += kc[r][e] * qe[e];
            kdq[r] = s;
        }
        #pragma unroll
        for (int e = 0; e < ETA_; ++e) nrm += sc[e] * qe[e];
        #pragma unroll
        for (int m = 1; m < 64; m <<= 1) {
            #pragma unroll
            for (int r = 0; r < R_; ++r) kdq[r] += __shfl_xor(kdq[r], m);
            nrm += __shfl_xor(nrm, m);
        }
        float kv = 0.f;
        #pragma unroll
        for (int r = 0; r < R_; ++r) kv += vc[r] * kdq[r];
        float at = kv / (2.f * R_ * nrm + 1e-5f);
        size_t oi = (size_t)t * (H_ * DH_) + h * DH_ + lane;
        u16 hi = f2bf(at);
        attnH[oi] = hi;
        attnL[oi] = f2bf(at - bf2f(hi));
    }
}

extern "C" void kernel_launch(void* const* d_in, const int* in_sizes, int n_in,
                              void* d_out, int out_size, void* d_ws, size_t ws_size,
                              hipStream_t stream) {
    const float* inputs = (const float*)d_in[0];
    const int*   term   = (const int*)d_in[1];
    const float* Wk     = (const float*)d_in[2];
    const float* bk     = (const float*)d_in[3];
    const float* Wp     = (const float*)d_in[4];
    const float* bp     = (const float*)d_in[5];
    const float* Wproj  = (const float*)d_in[6];
    const float* bproj  = (const float*)d_in[7];
    const float* TK     = (const float*)d_in[8];
    const float* TV     = (const float*)d_in[9];
    const float* SP     = (const float*)d_in[10];
    const float* tick   = (const float*)d_in[11];
    float* out = (float*)d_out;

    char* w = (char*)d_ws;
    u16* AbfH   = (u16*)w;  w += (size_t)S_ * D_ * 2;          // 8 MB
    u16* AbfL   = (u16*)w;  w += (size_t)S_ * D_ * 2;          // 8 MB
    u16* BbfH   = (u16*)w;  w += (size_t)D_ * N1_ * 2;         // 5.5 MB
    u16* BbfL   = (u16*)w;  w += (size_t)D_ * N1_ * 2;         // 5.5 MB
    u16* WpH    = (u16*)w;  w += (size_t)512 * D_ * 2;         // 1 MB
    u16* WpL    = (u16*)w;  w += (size_t)512 * D_ * 2;         // 1 MB
    u16* attnH  = (u16*)w;  w += (size_t)S_ * 512 * 2;         // 4 MB
    u16* attnL  = (u16*)w;  w += (size_t)S_ * 512 * 2;         // 4 MB
    float* biasb = (float*)w; w += (size_t)N1_ * 4;
    float* Y1   = (float*)w; w += (size_t)S_ * N1_ * 4;        // 44 MB
    float* OC   = (float*)w; w += (size_t)S_ * R_ * 4;
    float* CL   = (float*)w; w += (size_t)NC_ * H_ * 49 * 64 * 4;  // 12.8 MB
    float* CI   = (float*)w; w += (size_t)NC_ * H_ * 44 * 64 * 4;  // 11.5 MB

    cvt8_split<<<(S_ * D_ / 8 + 255) / 256, 256, 0, stream>>>(inputs, AbfH, AbfL, S_ * D_ / 8);
    cvt8_split<<<(512 * D_ / 8 + 255) / 256, 256, 0, stream>>>(Wproj, WpH, WpL, 512 * D_ / 8);
    prep_b1_split<<<(D_ * N1_ + 255) / 256, 256, 0, stream>>>(Wk, Wp, bk, bp, BbfH, BbfL, biasb);
    prep_oc<<<(S_ * R_ + 255) / 256, 256, 0, stream>>>(tick, OC);
    gemm_bf16x3<<<dim3(N1_ / 128, S_ / 128), 256, 0, stream>>>(AbfH, AbfL, D_, BbfH, BbfL, N1_, biasb, Y1, N1_, D_);
    scan_p1<<<NC_ * H_, 64, 0, stream>>>(Y1, OC, term, CL);
    scan_seq<<<H_, 64, 0, stream>>>(CL, CI, TK, TV, SP);
    scan_p3<<<NC_ * H_, 64, 0, stream>>>(Y1, OC, term, CI, attnH, attnL);
    gemm_bf16x3<<<dim3(D_ / 128, S_ / 128), 256, 0, stream>>>(attnH, attnL, 512, WpH, WpL, D_, bproj, out, D_, 512);
}

// Round 3
// 269.267 us; speedup vs baseline: 1.6264x; 1.6264x over previous
//
#include <hip/hip_runtime.h>
#include <hip/hip_bf16.h>

// ---- problem constants ----
#define S_    4096
#define D_    1024
#define H_    8
#define DH_   64
#define ETA_  4
#define R_    8
#define E_    256
#define NC_   128          // scan chunks
#define LC_   (S_/NC_)     // 32 steps per chunk
#define N1_   2688         // padded N for GEMM1 (21*128); cols: [0,2560)=kqvbg, [2560,2656)=p, rest zero
#define NKQV_ 2560
#define NP_   96
#define PIF   3.14159265358979323846

typedef unsigned short u16;
typedef short v8s __attribute__((ext_vector_type(8)));
typedef float v4f __attribute__((ext_vector_type(4)));

__device__ __forceinline__ u16 f2bf(float f) {
    unsigned u = __builtin_bit_cast(unsigned, f);
    return (u16)((u + 0x7FFFu + ((u >> 16) & 1u)) >> 16);
}
__device__ __forceinline__ float bf2f(u16 h) {
    return __builtin_bit_cast(float, (unsigned)h << 16);
}
__device__ __forceinline__ float sigm(float x) { return 1.f / (1.f + expf(-x)); }

// ---- prep: fp32 -> bf16 hi/lo split (8 elems/thread) ----
__global__ __launch_bounds__(256) void cvt8_split(const float* __restrict__ x,
                                                  u16* __restrict__ oh, u16* __restrict__ ol, int n8) {
    int i = blockIdx.x * 256 + threadIdx.x;
    if (i >= n8) return;
    const float4* xp = (const float4*)x;
    float4 a = xp[2 * i], b = xp[2 * i + 1];
    float v[8] = {a.x, a.y, a.z, a.w, b.x, b.y, b.z, b.w};
    unsigned hh[8], ll[8];
    #pragma unroll
    for (int j = 0; j < 8; ++j) {
        u16 h = f2bf(v[j]);
        hh[j] = h;
        ll[j] = f2bf(v[j] - bf2f(h));
    }
    uint4 rh, rl;
    rh.x = hh[0] | (hh[1] << 16); rh.y = hh[2] | (hh[3] << 16);
    rh.z = hh[4] | (hh[5] << 16); rh.w = hh[6] | (hh[7] << 16);
    rl.x = ll[0] | (ll[1] << 16); rl.y = ll[2] | (ll[3] << 16);
    rl.z = ll[4] | (ll[5] << 16); rl.w = ll[6] | (ll[7] << 16);
    ((uint4*)oh)[i] = rh;
    ((uint4*)ol)[i] = rl;
}

// ---- prep: combined B matrix [W_kqv | W_p | 0] (1024 x 2688) bf16 hi/lo + bias buffer ----
__global__ __launch_bounds__(256) void prep_b1_split(const float* __restrict__ Wk, const float* __restrict__ Wp,
                                                     const float* __restrict__ bk, const float* __restrict__ bp,
                                                     u16* __restrict__ BoH, u16* __restrict__ BoL,
                                                     float* __restrict__ biasb) {
    int idx = blockIdx.x * 256 + threadIdx.x;
    if (idx >= D_ * N1_) return;
    int k = idx / N1_, n = idx % N1_;
    float v = 0.f;
    if (n < NKQV_) v = Wk[(size_t)k * NKQV_ + n];
    else if (n < NKQV_ + NP_) v = Wp[(size_t)k * NP_ + (n - NKQV_)];
    u16 h = f2bf(v);
    BoH[idx] = h;
    BoL[idx] = f2bf(v - bf2f(h));
    if (k == 0) {
        float bv = 0.f;
        if (n < NKQV_) bv = bk[n];
        else if (n < NKQV_ + NP_) bv = bp[n - NKQV_];
        biasb[n] = bv;
    }
}

// ---- prep: oscillator table OC[t][r] = cos((tick0+t+1)*omega_r), replicating fp32 reference math ----
__global__ __launch_bounds__(256) void prep_oc(const float* __restrict__ tick, float* __restrict__ OC) {
    int idx = blockIdx.x * 256 + threadIdx.x;
    if (idx >= S_ * R_) return;
    int t = idx / R_, r = idx % R_;
    float start = (float)(-PIF), stop = (float)PIF;
    float step = __fdiv_rn(__fsub_rn(stop, start), 7.0f);
    float om = __fadd_rn(start, __fmul_rn((float)r, step));
    float tk = __fadd_rn(tick[0], (float)(t + 1));
    OC[idx] = cosf(__fmul_rn(tk, om));
}

// ---- split-bf16 MFMA GEMM: Y = (Ah+Al)(Bh+Bl) + bias, dropping lo*lo -> ~fp32 accurate ----
// 128x128 tile, 4 waves, 3 MFMA per fragment pair.
__global__ __launch_bounds__(256) void gemm_bf16x3(const u16* __restrict__ Ah, const u16* __restrict__ Al, int lda,
                                                   const u16* __restrict__ Bh, const u16* __restrict__ Bl, int ldb,
                                                   const float* __restrict__ bias,
                                                   float* __restrict__ Yo, int ldy, int Kdim) {
    __shared__ __align__(16) u16 AsH[128][56], AsL[128][56];   // row stride 112B
    __shared__ __align__(16) u16 BsH[128][56], BsL[128][56];   // transposed: Bs[n][k]
    const int tid = threadIdx.x;
    const int lane = tid & 63;
    const int w = tid >> 6;
    const int mw = (w >> 1) * 64, nw = (w & 1) * 64;
    const int m0 = blockIdx.y * 128, n0 = blockIdx.x * 128;
    const int l15 = lane & 15, lk = (lane >> 4) * 8;
    const int ar = tid >> 1, ac = (tid & 1) * 16;
    const int bk2 = (tid & 15) * 2, bn8 = (tid >> 4) * 8;
    v4f acc[4][4] = {};
    for (int k0 = 0; k0 < Kdim; k0 += 32) {
        const u16* Aph = Ah + (size_t)(m0 + ar) * lda + k0 + ac;
        const u16* Apl = Al + (size_t)(m0 + ar) * lda + k0 + ac;
        uint4 ah0 = *(const uint4*)Aph, ah1 = *(const uint4*)(Aph + 8);
        uint4 al0 = *(const uint4*)Apl, al1 = *(const uint4*)(Apl + 8);
        size_t bo0 = (size_t)(k0 + bk2) * ldb + n0 + bn8;
        size_t bo1 = bo0 + ldb;
        uint4 bh0 = *(const uint4*)(Bh + bo0), bh1 = *(const uint4*)(Bh + bo1);
        uint4 bl0 = *(const uint4*)(Bl + bo0), bl1 = *(const uint4*)(Bl + bo1);
        __syncthreads();
        *(uint4*)&AsH[ar][ac] = ah0; *(uint4*)&AsH[ar][ac + 8] = ah1;
        *(uint4*)&AsL[ar][ac] = al0; *(uint4*)&AsL[ar][ac + 8] = al1;
        union { uint4 v; u16 s[8]; } th0, th1, tl0, tl1;
        th0.v = bh0; th1.v = bh1; tl0.v = bl0; tl1.v = bl1;
        #pragma unroll
        for (int i = 0; i < 8; ++i) {
            *(unsigned*)&BsH[bn8 + i][bk2] = (unsigned)th0.s[i] | ((unsigned)th1.s[i] << 16);
            *(unsigned*)&BsL[bn8 + i][bk2] = (unsigned)tl0.s[i] | ((unsigned)tl1.s[i] << 16);
        }
        __syncthreads();
        v8s afh[4], afl[4], bfh[4], bfl[4];
        #pragma unroll
        for (int f = 0; f < 4; ++f) {
            afh[f] = *(const v8s*)&AsH[mw + f * 16 + l15][lk];
            afl[f] = *(const v8s*)&AsL[mw + f * 16 + l15][lk];
            bfh[f] = *(const v8s*)&BsH[nw + f * 16 + l15][lk];
            bfl[f] = *(const v8s*)&BsL[nw + f * 16 + l15][lk];
        }
        #pragma unroll
        for (int i = 0; i < 4; ++i)
            #pragma unroll
            for (int j = 0; j < 4; ++j) {
                acc[i][j] = __builtin_amdgcn_mfma_f32_16x16x32_bf16(afh[i], bfh[j], acc[i][j], 0, 0, 0);
                acc[i][j] = __builtin_amdgcn_mfma_f32_16x16x32_bf16(afl[i], bfh[j], acc[i][j], 0, 0, 0);
                acc[i][j] = __builtin_amdgcn_mfma_f32_16x16x32_bf16(afh[i], bfl[j], acc[i][j], 0, 0, 0);
            }
    }
    #pragma unroll
    for (int i = 0; i < 4; ++i) {
        int row0 = m0 + mw + i * 16 + (lane >> 4) * 4;   // C/D: col=lane&15, row=(lane>>4)*4+reg (m89)
        #pragma unroll
        for (int j = 0; j < 4; ++j) {
            int col = n0 + nw + j * 16 + l15;
            float bv = bias ? bias[col] : 0.f;
            #pragma unroll
            for (int rg = 0; rg < 4; ++rg)
                Yo[(size_t)(row0 + rg) * ldy + col] = acc[i][j][rg] + bv;
        }
    }
}

// ---- scan phase 1: per (chunk,head) local scan from zero + decay products ----
// CL record (49 vectors of 64 floats): [0,32)=kc[r*4+e], [32,40)=vc[r], [40,44)=sc[e], [44,48)=Pg[e], 48=Pb
__global__ __launch_bounds__(64) void scan_p1(const float* __restrict__ Y1, const float* __restrict__ OC,
                                              const int* __restrict__ term, float* __restrict__ CL) {
    const int b = blockIdx.x, c = b / H_, h = b % H_, lane = threadIdx.x;
    float kc[R_][ETA_] = {}, vc[R_] = {}, sc[ETA_] = {};
    float Pg[ETA_] = {1.f, 1.f, 1.f, 1.f}, Pb = 1.f;
    for (int t = c * LC_; t < c * LC_ + LC_; ++t) {
        const float* row = Y1 + (size_t)t * N1_;
        const float* bh = row + h * 320;
        float kk = bh[lane], vv = bh[128 + lane], bb = bh[192 + lane], gg = bh[256 + lane];
        const float* pp = row + NKQV_ + h * 12;
        float nt = 1.f - (float)term[t];
        float sb = sigm(bb), sg = sigm(gg);
        float rk = fmaxf(kk, 0.f);
        float vals = vv * sb, dbv = (1.f - sb) * nt;
        float occ[R_];
        #pragma unroll
        for (int r = 0; r < R_; ++r) occ[r] = OC[t * R_ + r];
        #pragma unroll
        for (int e = 0; e < ETA_; ++e) {
            float gam = sg * sigm(pp[8 + e]);
            float kg = rk * fmaxf(pp[e], 0.f) * gam;
            float dgv = (1.f - gam) * nt;
            sc[e] = dgv * sc[e] + kg;
            Pg[e] *= dgv;
            #pragma unroll
            for (int r = 0; r < R_; ++r) kc[r][e] = dgv * kc[r][e] + kg * occ[r];
        }
        Pb *= dbv;
        #pragma unroll
        for (int r = 0; r < R_; ++r) vc[r] = dbv * vc[r] + vals * occ[r];
    }
    float* out = CL + (size_t)b * 49 * 64;
    #pragma unroll
    for (int r = 0; r < R_; ++r)
        #pragma unroll
        for (int e = 0; e < ETA_; ++e) out[(r * 4 + e) * 64 + lane] = kc[r][e];
    #pragma unroll
    for (int r = 0; r < R_; ++r) out[(32 + r) * 64 + lane] = vc[r];
    #pragma unroll
    for (int e = 0; e < ETA_; ++e) out[(40 + e) * 64 + lane] = sc[e];
    #pragma unroll
    for (int e = 0; e < ETA_; ++e) out[(44 + e) * 64 + lane] = Pg[e];
    out[48 * 64 + lane] = Pb;
}

// ---- scan phase 2 (element-parallel): each thread owns one (h, vec, lane) state scalar ----
// x_{c+1} = d_c * x_c + cl_c ; CI[c] = x_c (carry-in). 8*44*64 = 22528 threads.
__global__ __launch_bounds__(256) void scan_comb(const float* __restrict__ CL, float* __restrict__ CI,
                                                 const float* __restrict__ TK, const float* __restrict__ TV,
                                                 const float* __restrict__ SP) {
    const int gid = blockIdx.x * 256 + threadIdx.x;
    const int lane = gid & 63;
    const int hv = gid >> 6;          // 0..351
    const int h = hv / 44;
    const int v = hv % 44;
    float x;
    int dvec;
    if (v < 32) {
        int r = v >> 2, e = v & 3;
        x = TK[((size_t)r * H_ + h) * E_ + lane * 4 + e];
        dvec = 44 + e;
    } else if (v < 40) {
        int r = v - 32;
        x = TV[((size_t)r * H_ + h) * DH_ + lane];
        dvec = 48;
    } else {
        int e = v - 40;
        x = SP[(size_t)h * E_ + lane * 4 + e];
        dvec = 44 + e;
    }
    const float* clb = CL + (size_t)h * 49 * 64 + (size_t)v * 64 + lane;
    const float* dcb = CL + (size_t)h * 49 * 64 + (size_t)dvec * 64 + lane;
    float* cib = CI + (size_t)h * 44 * 64 + (size_t)v * 64 + lane;
    const size_t sCL = (size_t)H_ * 49 * 64;
    const size_t sCI = (size_t)H_ * 44 * 64;
    #pragma unroll 8
    for (int c = 0; c < NC_; ++c) {
        cib[(size_t)c * sCI] = x;
        float cl = clb[(size_t)c * sCL];
        float d  = dcb[(size_t)c * sCL];
        x = fmaf(d, x, cl);
    }
}

// ---- scan phase 3: re-scan with carry-in, emit attn (bf16 hi/lo, S x 512) ----
__global__ __launch_bounds__(64) void scan_p3(const float* __restrict__ Y1, const float* __restrict__ OC,
                                              const int* __restrict__ term, const float* __restrict__ CI,
                                              u16* __restrict__ attnH, u16* __restrict__ attnL) {
    const int b = blockIdx.x, c = b / H_, h = b % H_, lane = threadIdx.x;
    float kc[R_][ETA_], vc[R_], sc[ETA_];
    const float* ci = CI + (size_t)b * 44 * 64;
    #pragma unroll
    for (int r = 0; r < R_; ++r)
        #pragma unroll
        for (int e = 0; e < ETA_; ++e) kc[r][e] = ci[(r * 4 + e) * 64 + lane];
    #pragma unroll
    for (int r = 0; r < R_; ++r) vc[r] = ci[(32 + r) * 64 + lane];
    #pragma unroll
    for (int e = 0; e < ETA_; ++e) sc[e] = ci[(40 + e) * 64 + lane];
    for (int t = c * LC_; t < c * LC_ + LC_; ++t) {
        const float* row = Y1 + (size_t)t * N1_;
        const float* bh = row + h * 320;
        float kk = bh[lane], qq = bh[64 + lane], vv = bh[128 + lane], bb = bh[192 + lane], gg = bh[256 + lane];
        const float* pp = row + NKQV_ + h * 12;
        float nt = 1.f - (float)term[t];
        float sb = sigm(bb), sg = sigm(gg);
        float rk = fmaxf(kk, 0.f), rq = fmaxf(qq, 0.f);
        float vals = vv * sb, dbv = (1.f - sb) * nt;
        float occ[R_];
        #pragma unroll
        for (int r = 0; r < R_; ++r) occ[r] = OC[t * R_ + r];
        float qe[ETA_];
        #pragma unroll
        for (int e = 0; e < ETA_; ++e) {
            float gam = sg * sigm(pp[8 + e]);
            float kg = rk * fmaxf(pp[e], 0.f) * gam;
            float dgv = (1.f - gam) * nt;
            qe[e] = rq * fmaxf(pp[4 + e], 0.f);
            sc[e] = dgv * sc[e] + kg;
            #pragma unroll
            for (int r = 0; r < R_; ++r) kc[r][e] = dgv * kc[r][e] + kg * occ[r];
        }
        #pragma unroll
        for (int r = 0; r < R_; ++r) vc[r] = dbv * vc[r] + vals * occ[r];
        float kdq[R_], nrm = 0.f;
        #pragma unroll
        for (int r = 0; r < R_; ++r) {
            float s = 0.f;
            #pragma unroll
            for (int e = 0; e < ETA_; ++e) s += kc[r][e] * qe[e];
            kdq[r] = s;
        }
        #pragma unroll
        for (int e = 0; e < ETA_; ++e) nrm += sc[e] * qe[e];
        #pragma unroll
        for (int m = 1; m < 64; m <<= 1) {
            #pragma unroll
            for (int r = 0; r < R_; ++r) kdq[r] += __shfl_xor(kdq[r], m);
            nrm += __shfl_xor(nrm, m);
        }
        float kv = 0.f;
        #pragma unroll
        for (int r = 0; r < R_; ++r) kv += vc[r] * kdq[r];
        float at = kv / (2.f * R_ * nrm + 1e-5f);
        size_t oi = (size_t)t * (H_ * DH_) + h * DH_ + lane;
        u16 hi = f2bf(at);
        attnH[oi] = hi;
        attnL[oi] = f2bf(at - bf2f(hi));
    }
}

extern "C" void kernel_launch(void* const* d_in, const int* in_sizes, int n_in,
                              void* d_out, int out_size, void* d_ws, size_t ws_size,
                              hipStream_t stream) {
    const float* inputs = (const float*)d_in[0];
    const int*   term   = (const int*)d_in[1];
    const float* Wk     = (const float*)d_in[2];
    const float* bk     = (const float*)d_in[3];
    const float* Wp     = (const float*)d_in[4];
    const float* bp     = (const float*)d_in[5];
    const float* Wproj  = (const float*)d_in[6];
    const float* bproj  = (const float*)d_in[7];
    const float* TK     = (const float*)d_in[8];
    const float* TV     = (const float*)d_in[9];
    const float* SP     = (const float*)d_in[10];
    const float* tick   = (const float*)d_in[11];
    float* out = (float*)d_out;

    char* w = (char*)d_ws;
    u16* AbfH   = (u16*)w;  w += (size_t)S_ * D_ * 2;          // 8 MB
    u16* AbfL   = (u16*)w;  w += (size_t)S_ * D_ * 2;          // 8 MB
    u16* BbfH   = (u16*)w;  w += (size_t)D_ * N1_ * 2;         // 5.5 MB
    u16* BbfL   = (u16*)w;  w += (size_t)D_ * N1_ * 2;         // 5.5 MB
    u16* WpH    = (u16*)w;  w += (size_t)512 * D_ * 2;         // 1 MB
    u16* WpL    = (u16*)w;  w += (size_t)512 * D_ * 2;         // 1 MB
    u16* attnH  = (u16*)w;  w += (size_t)S_ * 512 * 2;         // 4 MB
    u16* attnL  = (u16*)w;  w += (size_t)S_ * 512 * 2;         // 4 MB
    float* biasb = (float*)w; w += (size_t)N1_ * 4;
    float* Y1   = (float*)w; w += (size_t)S_ * N1_ * 4;        // 44 MB
    float* OC   = (float*)w; w += (size_t)S_ * R_ * 4;
    float* CL   = (float*)w; w += (size_t)NC_ * H_ * 49 * 64 * 4;  // 12.8 MB
    float* CI   = (float*)w; w += (size_t)NC_ * H_ * 44 * 64 * 4;  // 11.5 MB

    cvt8_split<<<(S_ * D_ / 8 + 255) / 256, 256, 0, stream>>>(inputs, AbfH, AbfL, S_ * D_ / 8);
    cvt8_split<<<(512 * D_ / 8 + 255) / 256, 256, 0, stream>>>(Wproj, WpH, WpL, 512 * D_ / 8);
    prep_b1_split<<<(D_ * N1_ + 255) / 256, 256, 0, stream>>>(Wk, Wp, bk, bp, BbfH, BbfL, biasb);
    prep_oc<<<(S_ * R_ + 255) / 256, 256, 0, stream>>>(tick, OC);
    gemm_bf16x3<<<dim3(N1_ / 128, S_ / 128), 256, 0, stream>>>(AbfH, AbfL, D_, BbfH, BbfL, N1_, biasb, Y1, N1_, D_);
    scan_p1<<<NC_ * H_, 64, 0, stream>>>(Y1, OC, term, CL);
    scan_comb<<<(H_ * 44 * 64) / 256, 256, 0, stream>>>(CL, CI, TK, TV, SP);
    scan_p3<<<NC_ * H_, 64, 0, stream>>>(Y1, OC, term, CI, attnH, attnL);
    gemm_bf16x3<<<dim3(D_ / 128, S_ / 128), 256, 0, stream>>>(attnH, attnL, 512, WpH, WpL, D_, bproj, out, D_, 512);
}

// Round 4
// 231.486 us; speedup vs baseline: 1.8919x; 1.1632x over previous
//
#include <hip/hip_runtime.h>
#include <hip/hip_bf16.h>

// ---- problem constants ----
#define S_    4096
#define D_    1024
#define H_    8
#define DH_   64
#define ETA_  4
#define R_    8
#define E_    256
#define NC_   128          // scan chunks
#define LC_   (S_/NC_)     // 32 steps per chunk
#define N1_   2688         // padded N for GEMM1 (21*128); cols: [0,2560)=kqvbg, [2560,2656)=p, rest zero
#define NKQV_ 2560
#define NP_   96
#define PIF   3.14159265358979323846

typedef unsigned short u16;
typedef unsigned int   u32;
typedef short v8s __attribute__((ext_vector_type(8)));
typedef float v4f __attribute__((ext_vector_type(4)));

__device__ __forceinline__ u16 f2bf(float f) {
    unsigned u = __builtin_bit_cast(unsigned, f);
    return (u16)((u + 0x7FFFu + ((u >> 16) & 1u)) >> 16);
}
__device__ __forceinline__ float bf2f(u16 h) {
    return __builtin_bit_cast(float, (unsigned)h << 16);
}
__device__ __forceinline__ float sigm(float x) { return 1.f / (1.f + expf(-x)); }

// async global->LDS, 16 B per lane; LDS dest = wave-uniform base + lane*16
#define GLD16(gp, lp) __builtin_amdgcn_global_load_lds( \
    (const __attribute__((address_space(1))) u32*)(const void*)(gp), \
    (__attribute__((address_space(3))) u32*)(void*)(lp), 16, 0, 0)

// ---- prep: fp32 -> bf16 hi/lo split (8 elems/thread), row-major ----
__global__ __launch_bounds__(256) void cvt8_split(const float* __restrict__ x,
                                                  u16* __restrict__ oh, u16* __restrict__ ol, int n8) {
    int i = blockIdx.x * 256 + threadIdx.x;
    if (i >= n8) return;
    const float4* xp = (const float4*)x;
    float4 a = xp[2 * i], b = xp[2 * i + 1];
    float v[8] = {a.x, a.y, a.z, a.w, b.x, b.y, b.z, b.w};
    unsigned hh[8], ll[8];
    #pragma unroll
    for (int j = 0; j < 8; ++j) {
        u16 h = f2bf(v[j]);
        hh[j] = h;
        ll[j] = f2bf(v[j] - bf2f(h));
    }
    uint4 rh, rl;
    rh.x = hh[0] | (hh[1] << 16); rh.y = hh[2] | (hh[3] << 16);
    rh.z = hh[4] | (hh[5] << 16); rh.w = hh[6] | (hh[7] << 16);
    rl.x = ll[0] | (ll[1] << 16); rl.y = ll[2] | (ll[3] << 16);
    rl.z = ll[4] | (ll[5] << 16); rl.w = ll[6] | (ll[7] << 16);
    ((uint4*)oh)[i] = rh;
    ((uint4*)ol)[i] = rl;
}

// ---- prep: transpose + hi/lo split. src fp32 [K][Nsrc] row-major -> dst u16 [n][K] at rowOff.
// grid: (K/64, nTiles64); cols >= Nsrc write 0.
__global__ __launch_bounds__(256) void tr_split(const float* __restrict__ src, int K, int Nsrc,
                                                u16* __restrict__ dH, u16* __restrict__ dL, int rowOff) {
    __shared__ float tile[64][65];
    const int k0 = blockIdx.x * 64, n0 = blockIdx.y * 64;
    const int t = threadIdx.x, cc = t & 63, rr = t >> 6;
    #pragma unroll
    for (int i = 0; i < 16; ++i) {
        int kk = rr * 16 + i;
        float v = (n0 + cc < Nsrc) ? src[(size_t)(k0 + kk) * Nsrc + n0 + cc] : 0.f;
        tile[kk][cc] = v;
    }
    __syncthreads();
    #pragma unroll
    for (int i = 0; i < 16; ++i) {
        int nn = rr * 16 + i;
        float v = tile[cc][nn];
        u16 h = f2bf(v);
        size_t o = (size_t)(rowOff + n0 + nn) * K + k0 + cc;
        dH[o] = h;
        dL[o] = f2bf(v - bf2f(h));
    }
}

// ---- prep: bias for GEMM1 ----
__global__ __launch_bounds__(256) void prep_bias1(const float* __restrict__ bk, const float* __restrict__ bp,
                                                  float* __restrict__ biasb) {
    int n = blockIdx.x * 256 + threadIdx.x;
    if (n >= N1_) return;
    biasb[n] = n < NKQV_ ? bk[n] : (n < NKQV_ + NP_ ? bp[n - NKQV_] : 0.f);
}

// ---- prep: oscillator table OC[t][r] = cos((tick0+t+1)*omega_r), replicating fp32 reference math ----
__global__ __launch_bounds__(256) void prep_oc(const float* __restrict__ tick, float* __restrict__ OC) {
    int idx = blockIdx.x * 256 + threadIdx.x;
    if (idx >= S_ * R_) return;
    int t = idx / R_, r = idx % R_;
    float start = (float)(-PIF), stop = (float)PIF;
    float step = __fdiv_rn(__fsub_rn(stop, start), 7.0f);
    float om = __fadd_rn(start, __fmul_rn((float)r, step));
    float tk = __fadd_rn(tick[0], (float)(t + 1));
    OC[idx] = cosf(__fmul_rn(tk, om));
}

// ---- split-bf16 MFMA GEMM: Y = (Ah+Al)(Bh+Bl) + bias (lo*lo dropped) ----
// A: [M][K] u16 row-major (hi/lo). BT: [N][K] u16 row-major (hi/lo). 128x128 tile, 4 waves.
// global_load_lds(16B) staging into double-buffered LDS; XOR slot swizzle on (source, ds_read) pair.
__global__ __launch_bounds__(256, 2) void gemm_x3_lds(const u16* __restrict__ Ah, const u16* __restrict__ Al,
                                                      const u16* __restrict__ BTh, const u16* __restrict__ BTl,
                                                      const float* __restrict__ bias,
                                                      float* __restrict__ Yo, int ldy, int Kdim) {
    __shared__ __align__(16) u16 lds[2][4][4096];   // 2 buf x {AH,AL,BH,BL} x [128 rows][32 k] = 64 KB
    const int tid = threadIdx.x, lane = tid & 63, w = tid >> 6;
    const int mw = (w >> 1) * 64, nw = (w & 1) * 64;
    const int l15 = lane & 15, lk8 = lane >> 4;
    const int lke = (lk8 ^ (l15 & 3) ^ ((l15 >> 2) & 3)) * 8;   // swizzled k-slot for frag reads
    // XCD-aware block swizzle (requires nb % 8 == 0)
    const int gx = gridDim.x;
    const int nb = gx * gridDim.y;
    const int orig = blockIdx.y * gx + blockIdx.x;
    const int per = nb >> 3;
    const int swz = (orig & 7) * per + (orig >> 3);
    const int m0 = (swz / gx) * 128, n0 = (swz % gx) * 128;
    const int nk = Kdim >> 5;

    auto stage = [&](int buf, int k0) {
        #pragma unroll
        for (int c = 0; c < 2; ++c) {
            int u = tid + (c << 8);
            int row = u >> 2, s = u & 3;
            int kc = ((s ^ (row & 3) ^ ((row >> 2) & 3)) << 3);  // pre-swizzled global chunk
            int wub = ((u & ~63) << 3);                           // wave-uniform LDS elem offset
            size_t offA = (size_t)(m0 + row) * Kdim + k0 + kc;
            size_t offB = (size_t)(n0 + row) * Kdim + k0 + kc;
            GLD16(Ah  + offA, &lds[buf][0][wub]);
            GLD16(Al  + offA, &lds[buf][1][wub]);
            GLD16(BTh + offB, &lds[buf][2][wub]);
            GLD16(BTl + offB, &lds[buf][3][wub]);
        }
    };

    v4f acc[4][4] = {};
    stage(0, 0);
    int cur = 0;
    for (int kt = 0; kt < nk; ++kt) {
        __syncthreads();                      // drains vmcnt: buf[cur] staged; prev frag reads done
        if (kt + 1 < nk) stage(cur ^ 1, (kt + 1) << 5);
        v8s afh[4], afl[4], bfh[4], bfl[4];
        #pragma unroll
        for (int f = 0; f < 4; ++f) {
            int ra = (mw + f * 16 + l15) * 32 + lke;
            int rb = (nw + f * 16 + l15) * 32 + lke;
            afh[f] = *(const v8s*)&lds[cur][0][ra];
            afl[f] = *(const v8s*)&lds[cur][1][ra];
            bfh[f] = *(const v8s*)&lds[cur][2][rb];
            bfl[f] = *(const v8s*)&lds[cur][3][rb];
        }
        #pragma unroll
        for (int i = 0; i < 4; ++i)
            #pragma unroll
            for (int j = 0; j < 4; ++j) {
                acc[i][j] = __builtin_amdgcn_mfma_f32_16x16x32_bf16(afh[i], bfh[j], acc[i][j], 0, 0, 0);
                acc[i][j] = __builtin_amdgcn_mfma_f32_16x16x32_bf16(afl[i], bfh[j], acc[i][j], 0, 0, 0);
                acc[i][j] = __builtin_amdgcn_mfma_f32_16x16x32_bf16(afh[i], bfl[j], acc[i][j], 0, 0, 0);
            }
        cur ^= 1;
    }
    #pragma unroll
    for (int i = 0; i < 4; ++i) {
        int row0 = m0 + mw + i * 16 + lk8 * 4;   // C/D: col=lane&15, row=(lane>>4)*4+reg (m89)
        #pragma unroll
        for (int j = 0; j < 4; ++j) {
            int col = n0 + nw + j * 16 + l15;
            float bv = bias ? bias[col] : 0.f;
            #pragma unroll
            for (int rg = 0; rg < 4; ++rg)
                Yo[(size_t)(row0 + rg) * ldy + col] = acc[i][j][rg] + bv;
        }
    }
}

// ---- scan phase 1: per (chunk,head) local scan from zero + decay products ----
// CL record (49 vectors of 64 floats): [0,32)=kc[r*4+e], [32,40)=vc[r], [40,44)=sc[e], [44,48)=Pg[e], 48=Pb
__global__ __launch_bounds__(64) void scan_p1(const float* __restrict__ Y1, const float* __restrict__ OC,
                                              const int* __restrict__ term, float* __restrict__ CL) {
    const int b = blockIdx.x, c = b / H_, h = b % H_, lane = threadIdx.x;
    float kc[R_][ETA_] = {}, vc[R_] = {}, sc[ETA_] = {};
    float Pg[ETA_] = {1.f, 1.f, 1.f, 1.f}, Pb = 1.f;
    for (int t = c * LC_; t < c * LC_ + LC_; ++t) {
        const float* row = Y1 + (size_t)t * N1_;
        const float* bh = row + h * 320;
        float kk = bh[lane], vv = bh[128 + lane], bb = bh[192 + lane], gg = bh[256 + lane];
        const float* pp = row + NKQV_ + h * 12;
        float nt = 1.f - (float)term[t];
        float sb = sigm(bb), sg = sigm(gg);
        float rk = fmaxf(kk, 0.f);
        float vals = vv * sb, dbv = (1.f - sb) * nt;
        float occ[R_];
        #pragma unroll
        for (int r = 0; r < R_; ++r) occ[r] = OC[t * R_ + r];
        #pragma unroll
        for (int e = 0; e < ETA_; ++e) {
            float gam = sg * sigm(pp[8 + e]);
            float kg = rk * fmaxf(pp[e], 0.f) * gam;
            float dgv = (1.f - gam) * nt;
            sc[e] = dgv * sc[e] + kg;
            Pg[e] *= dgv;
            #pragma unroll
            for (int r = 0; r < R_; ++r) kc[r][e] = dgv * kc[r][e] + kg * occ[r];
        }
        Pb *= dbv;
        #pragma unroll
        for (int r = 0; r < R_; ++r) vc[r] = dbv * vc[r] + vals * occ[r];
    }
    float* out = CL + (size_t)b * 49 * 64;
    #pragma unroll
    for (int r = 0; r < R_; ++r)
        #pragma unroll
        for (int e = 0; e < ETA_; ++e) out[(r * 4 + e) * 64 + lane] = kc[r][e];
    #pragma unroll
    for (int r = 0; r < R_; ++r) out[(32 + r) * 64 + lane] = vc[r];
    #pragma unroll
    for (int e = 0; e < ETA_; ++e) out[(40 + e) * 64 + lane] = sc[e];
    #pragma unroll
    for (int e = 0; e < ETA_; ++e) out[(44 + e) * 64 + lane] = Pg[e];
    out[48 * 64 + lane] = Pb;
}

// ---- scan phase 2 (element-parallel): each thread owns one (h, vec, lane) state scalar ----
__global__ __launch_bounds__(256) void scan_comb(const float* __restrict__ CL, float* __restrict__ CI,
                                                 const float* __restrict__ TK, const float* __restrict__ TV,
                                                 const float* __restrict__ SP) {
    const int gid = blockIdx.x * 256 + threadIdx.x;
    const int lane = gid & 63;
    const int hv = gid >> 6;          // 0..351
    const int h = hv / 44;
    const int v = hv % 44;
    float x;
    int dvec;
    if (v < 32) {
        int r = v >> 2, e = v & 3;
        x = TK[((size_t)r * H_ + h) * E_ + lane * 4 + e];
        dvec = 44 + e;
    } else if (v < 40) {
        int r = v - 32;
        x = TV[((size_t)r * H_ + h) * DH_ + lane];
        dvec = 48;
    } else {
        int e = v - 40;
        x = SP[(size_t)h * E_ + lane * 4 + e];
        dvec = 44 + e;
    }
    const float* clb = CL + (size_t)h * 49 * 64 + (size_t)v * 64 + lane;
    const float* dcb = CL + (size_t)h * 49 * 64 + (size_t)dvec * 64 + lane;
    float* cib = CI + (size_t)h * 44 * 64 + (size_t)v * 64 + lane;
    const size_t sCL = (size_t)H_ * 49 * 64;
    const size_t sCI = (size_t)H_ * 44 * 64;
    #pragma unroll 8
    for (int c = 0; c < NC_; ++c) {
        cib[(size_t)c * sCI] = x;
        float cl = clb[(size_t)c * sCL];
        float d  = dcb[(size_t)c * sCL];
        x = fmaf(d, x, cl);
    }
}

// ---- scan phase 3: re-scan with carry-in, emit attn (bf16 hi/lo, S x 512) ----
__global__ __launch_bounds__(64) void scan_p3(const float* __restrict__ Y1, const float* __restrict__ OC,
                                              const int* __restrict__ term, const float* __restrict__ CI,
                                              u16* __restrict__ attnH, u16* __restrict__ attnL) {
    const int b = blockIdx.x, c = b / H_, h = b % H_, lane = threadIdx.x;
    float kc[R_][ETA_], vc[R_], sc[ETA_];
    const float* ci = CI + (size_t)b * 44 * 64;
    #pragma unroll
    for (int r = 0; r < R_; ++r)
        #pragma unroll
        for (int e = 0; e < ETA_; ++e) kc[r][e] = ci[(r * 4 + e) * 64 + lane];
    #pragma unroll
    for (int r = 0; r < R_; ++r) vc[r] = ci[(32 + r) * 64 + lane];
    #pragma unroll
    for (int e = 0; e < ETA_; ++e) sc[e] = ci[(40 + e) * 64 + lane];
    for (int t = c * LC_; t < c * LC_ + LC_; ++t) {
        const float* row = Y1 + (size_t)t * N1_;
        const float* bh = row + h * 320;
        float kk = bh[lane], qq = bh[64 + lane], vv = bh[128 + lane], bb = bh[192 + lane], gg = bh[256 + lane];
        const float* pp = row + NKQV_ + h * 12;
        float nt = 1.f - (float)term[t];
        float sb = sigm(bb), sg = sigm(gg);
        float rk = fmaxf(kk, 0.f), rq = fmaxf(qq, 0.f);
        float vals = vv * sb, dbv = (1.f - sb) * nt;
        float occ[R_];
        #pragma unroll
        for (int r = 0; r < R_; ++r) occ[r] = OC[t * R_ + r];
        float qe[ETA_];
        #pragma unroll
        for (int e = 0; e < ETA_; ++e) {
            float gam = sg * sigm(pp[8 + e]);
            float kg = rk * fmaxf(pp[e], 0.f) * gam;
            float dgv = (1.f - gam) * nt;
            qe[e] = rq * fmaxf(pp[4 + e], 0.f);
            sc[e] = dgv * sc[e] + kg;
            #pragma unroll
            for (int r = 0; r < R_; ++r) kc[r][e] = dgv * kc[r][e] + kg * occ[r];
        }
        #pragma unroll
        for (int r = 0; r < R_; ++r) vc[r] = dbv * vc[r] + vals * occ[r];
        float kdq[R_], nrm = 0.f;
        #pragma unroll
        for (int r = 0; r < R_; ++r) {
            float s = 0.f;
            #pragma unroll
            for (int e = 0; e < ETA_; ++e) s += kc[r][e] * qe[e];
            kdq[r] = s;
        }
        #pragma unroll
        for (int e = 0; e < ETA_; ++e) nrm += sc[e] * qe[e];
        #pragma unroll
        for (int m = 1; m < 64; m <<= 1) {
            #pragma unroll
            for (int r = 0; r < R_; ++r) kdq[r] += __shfl_xor(kdq[r], m);
            nrm += __shfl_xor(nrm, m);
        }
        float kv = 0.f;
        #pragma unroll
        for (int r = 0; r < R_; ++r) kv += vc[r] * kdq[r];
        float at = kv / (2.f * R_ * nrm + 1e-5f);
        size_t oi = (size_t)t * (H_ * DH_) + h * DH_ + lane;
        u16 hi = f2bf(at);
        attnH[oi] = hi;
        attnL[oi] = f2bf(at - bf2f(hi));
    }
}

extern "C" void kernel_launch(void* const* d_in, const int* in_sizes, int n_in,
                              void* d_out, int out_size, void* d_ws, size_t ws_size,
                              hipStream_t stream) {
    const float* inputs = (const float*)d_in[0];
    const int*   term   = (const int*)d_in[1];
    const float* Wk     = (const float*)d_in[2];
    const float* bk     = (const float*)d_in[3];
    const float* Wp     = (const float*)d_in[4];
    const float* bp     = (const float*)d_in[5];
    const float* Wproj  = (const float*)d_in[6];
    const float* bproj  = (const float*)d_in[7];
    const float* TK     = (const float*)d_in[8];
    const float* TV     = (const float*)d_in[9];
    const float* SP     = (const float*)d_in[10];
    const float* tick   = (const float*)d_in[11];
    float* out = (float*)d_out;

    char* w = (char*)d_ws;
    u16* AbfH   = (u16*)w;  w += (size_t)S_ * D_ * 2;          // 8 MB
    u16* AbfL   = (u16*)w;  w += (size_t)S_ * D_ * 2;          // 8 MB
    u16* BTh    = (u16*)w;  w += (size_t)N1_ * D_ * 2;         // 5.5 MB  [n][k]
    u16* BTl    = (u16*)w;  w += (size_t)N1_ * D_ * 2;         // 5.5 MB
    u16* WpTh   = (u16*)w;  w += (size_t)D_ * 512 * 2;         // 1 MB    [n][k]
    u16* WpTl   = (u16*)w;  w += (size_t)D_ * 512 * 2;         // 1 MB
    u16* attnH  = (u16*)w;  w += (size_t)S_ * 512 * 2;         // 4 MB
    u16* attnL  = (u16*)w;  w += (size_t)S_ * 512 * 2;         // 4 MB
    float* biasb = (float*)w; w += (size_t)N1_ * 4;
    float* Y1   = (float*)w; w += (size_t)S_ * N1_ * 4;        // 44 MB
    float* OC   = (float*)w; w += (size_t)S_ * R_ * 4;
    float* CL   = (float*)w; w += (size_t)NC_ * H_ * 49 * 64 * 4;  // 12.8 MB
    float* CI   = (float*)w; w += (size_t)NC_ * H_ * 44 * 64 * 4;  // 11.5 MB

    cvt8_split<<<(S_ * D_ / 8 + 255) / 256, 256, 0, stream>>>(inputs, AbfH, AbfL, S_ * D_ / 8);
    tr_split<<<dim3(D_ / 64, NKQV_ / 64), 256, 0, stream>>>(Wk, D_, NKQV_, BTh, BTl, 0);
    tr_split<<<dim3(D_ / 64, 2), 256, 0, stream>>>(Wp, D_, NP_, BTh, BTl, NKQV_);
    tr_split<<<dim3(512 / 64, D_ / 64), 256, 0, stream>>>(Wproj, 512, D_, WpTh, WpTl, 0);
    prep_bias1<<<(N1_ + 255) / 256, 256, 0, stream>>>(bk, bp, biasb);
    prep_oc<<<(S_ * R_ + 255) / 256, 256, 0, stream>>>(tick, OC);
    gemm_x3_lds<<<dim3(N1_ / 128, S_ / 128), 256, 0, stream>>>(AbfH, AbfL, BTh, BTl, biasb, Y1, N1_, D_);
    scan_p1<<<NC_ * H_, 64, 0, stream>>>(Y1, OC, term, CL);
    scan_comb<<<(H_ * 44 * 64) / 256, 256, 0, stream>>>(CL, CI, TK, TV, SP);
    scan_p3<<<NC_ * H_, 64, 0, stream>>>(Y1, OC, term, CI, attnH, attnL);
    gemm_x3_lds<<<dim3(1024 / 128, S_ / 128), 256, 0, stream>>>(attnH, attnL, WpTh, WpTl, bproj, out, D_, 512);
}

// Round 5
// 205.752 us; speedup vs baseline: 2.1285x; 1.1251x over previous
//
#include <hip/hip_runtime.h>
#include <hip/hip_bf16.h>

// ---- problem constants ----
#define S_    4096
#define D_    1024
#define H_    8
#define DH_   64
#define ETA_  4
#define R_    8
#define E_    256
#define NC_   128          // scan chunks
#define LC_   (S_/NC_)     // 32 steps per chunk
#define N1_   2688         // padded N for GEMM1 (21*128)
#define NKQV_ 2560
#define NP_   96
#define PIF   3.14159265358979323846

// prep_all block-range boundaries
#define PB_CVT    2048                 // inputs fp32->bf16 split
#define PB_TRWK   (PB_CVT + 640)       // W_kqv transpose (16 k-tiles x 40 n-tiles)
#define PB_TRWP   (PB_TRWK + 32)       // W_p transpose (16 x 2)
#define PB_TRWPJ  (PB_TRWP + 128)      // W_proj transpose (8 x 16)
#define PB_OC     (PB_TRWPJ + 128)     // oscillator table
#define PB_BIAS   (PB_OC + 11)         // bias1
#define PB_TOTAL  PB_BIAS

typedef unsigned short u16;
typedef unsigned int   u32;
typedef short v8s __attribute__((ext_vector_type(8)));
typedef float v4f __attribute__((ext_vector_type(4)));

__device__ __forceinline__ u16 f2bf(float f) {
    unsigned u = __builtin_bit_cast(unsigned, f);
    return (u16)((u + 0x7FFFu + ((u >> 16) & 1u)) >> 16);
}
__device__ __forceinline__ float bf2f(u16 h) {
    return __builtin_bit_cast(float, (unsigned)h << 16);
}
__device__ __forceinline__ float sigm(float x) { return 1.f / (1.f + expf(-x)); }

// async global->LDS, 16 B per lane; LDS dest = wave-uniform base + lane*16
#define GLD16(gp, lp) __builtin_amdgcn_global_load_lds( \
    (const __attribute__((address_space(1))) u32*)(const void*)(gp), \
    (__attribute__((address_space(3))) u32*)(void*)(lp), 16, 0, 0)

// ---- transpose+split 64x64 tile helper (shared tile passed in) ----
__device__ __forceinline__ void tr64(float (*tile)[65], const float* __restrict__ src, int K, int Nsrc,
                                     u16* __restrict__ dH, u16* __restrict__ dL, int rowOff,
                                     int k0, int n0, int t) {
    const int cc = t & 63, rr = t >> 6;
    #pragma unroll
    for (int i = 0; i < 16; ++i) {
        int kk = rr * 16 + i;
        tile[kk][cc] = (n0 + cc < Nsrc) ? src[(size_t)(k0 + kk) * Nsrc + n0 + cc] : 0.f;
    }
    __syncthreads();
    #pragma unroll
    for (int i = 0; i < 16; ++i) {
        int nn = rr * 16 + i;
        float v = tile[cc][nn];
        u16 h = f2bf(v);
        size_t o = (size_t)(rowOff + n0 + nn) * K + k0 + cc;
        dH[o] = h;
        dL[o] = f2bf(v - bf2f(h));
    }
}

// ---- fused prep: cvt inputs, 3 transposes, oscillator table, bias ----
__global__ __launch_bounds__(256) void prep_all(const float* __restrict__ inputs,
                                                const float* __restrict__ Wk, const float* __restrict__ Wp,
                                                const float* __restrict__ Wproj,
                                                const float* __restrict__ bk, const float* __restrict__ bp,
                                                const float* __restrict__ tick,
                                                u16* __restrict__ AbfH, u16* __restrict__ AbfL,
                                                u16* __restrict__ BTh, u16* __restrict__ BTl,
                                                u16* __restrict__ WpTh, u16* __restrict__ WpTl,
                                                float* __restrict__ biasb, float* __restrict__ OC) {
    __shared__ float tile[64][65];
    const int b = blockIdx.x, t = threadIdx.x;
    if (b < PB_CVT) {
        int i = b * 256 + t;                       // 8 elems per thread
        const float4* xp = (const float4*)inputs;
        float4 a = xp[2 * i], bb = xp[2 * i + 1];
        float v[8] = {a.x, a.y, a.z, a.w, bb.x, bb.y, bb.z, bb.w};
        unsigned hh[8], ll[8];
        #pragma unroll
        for (int j = 0; j < 8; ++j) {
            u16 h = f2bf(v[j]);
            hh[j] = h;
            ll[j] = f2bf(v[j] - bf2f(h));
        }
        uint4 rh, rl;
        rh.x = hh[0] | (hh[1] << 16); rh.y = hh[2] | (hh[3] << 16);
        rh.z = hh[4] | (hh[5] << 16); rh.w = hh[6] | (hh[7] << 16);
        rl.x = ll[0] | (ll[1] << 16); rl.y = ll[2] | (ll[3] << 16);
        rl.z = ll[4] | (ll[5] << 16); rl.w = ll[6] | (ll[7] << 16);
        ((uint4*)AbfH)[i] = rh;
        ((uint4*)AbfL)[i] = rl;
    } else if (b < PB_TRWK) {
        int i = b - PB_CVT;
        tr64(tile, Wk, D_, NKQV_, BTh, BTl, 0, (i % 16) * 64, (i / 16) * 64, t);
    } else if (b < PB_TRWP) {
        int i = b - PB_TRWK;
        tr64(tile, Wp, D_, NP_, BTh, BTl, NKQV_, (i % 16) * 64, (i / 16) * 64, t);
    } else if (b < PB_TRWPJ) {
        int i = b - PB_TRWP;
        tr64(tile, Wproj, 512, D_, WpTh, WpTl, 0, (i % 8) * 64, (i / 8) * 64, t);
    } else if (b < PB_OC) {
        int idx = (b - PB_TRWPJ) * 256 + t;        // t in [0, S*R)
        int tt = idx / R_, r = idx % R_;
        float start = (float)(-PIF), stop = (float)PIF;
        float step = __fdiv_rn(__fsub_rn(stop, start), 7.0f);
        float om = __fadd_rn(start, __fmul_rn((float)r, step));
        float tk = __fadd_rn(tick[0], (float)(tt + 1));
        OC[idx] = cosf(__fmul_rn(tk, om));
    } else {
        int n = (b - PB_OC) * 256 + t;
        if (n < N1_)
            biasb[n] = n < NKQV_ ? bk[n] : (n < NKQV_ + NP_ ? bp[n - NKQV_] : 0.f);
    }
}

// ---- split-bf16 MFMA GEMM with counted-vmcnt pipeline ----
// Y = (Ah+Al)(Bh+Bl) + bias (lo*lo dropped). A:[M][K], BT:[N][K] u16 row-major.
// 128x128 tile, 4 waves, BK=32, double-buffered LDS via global_load_lds(16B).
// Schedule per K-step: B1 -> stage(kt+1) -> vmcnt(8) -> B2 -> ds_read+48 MFMA.
// actMode=1: GEMM1 column-typed activation fused into epilogue.
__global__ __launch_bounds__(256, 2) void gemm_x3_pipe(const u16* __restrict__ Ah, const u16* __restrict__ Al,
                                                       const u16* __restrict__ BTh, const u16* __restrict__ BTl,
                                                       const float* __restrict__ bias,
                                                       float* __restrict__ Yo, int ldy, int Kdim, int actMode) {
    __shared__ __align__(16) u16 lds[2][4][4096];   // 2 buf x {AH,AL,BH,BL} x [128][32] = 64 KB
    const int tid = threadIdx.x, lane = tid & 63, w = tid >> 6;
    const int mw = (w >> 1) * 64, nw = (w & 1) * 64;
    const int l15 = lane & 15, lk8 = lane >> 4;
    const int lke = (lk8 ^ (l15 & 3) ^ ((l15 >> 2) & 3)) * 8;   // swizzled k-slot for frag reads
    // XCD-aware block swizzle (requires total blocks % 8 == 0)
    const int gx = gridDim.x;
    const int nb = gx * gridDim.y;
    const int orig = blockIdx.y * gx + blockIdx.x;
    const int per = nb >> 3;
    const int swz = (orig & 7) * per + (orig >> 3);
    const int m0 = (swz / gx) * 128, n0 = (swz % gx) * 128;
    const int nk = Kdim >> 5;

    auto stage = [&](int buf, int k0) {
        #pragma unroll
        for (int c = 0; c < 2; ++c) {
            int u = tid + (c << 8);
            int row = u >> 2, s = u & 3;
            int kc = ((s ^ (row & 3) ^ ((row >> 2) & 3)) << 3);  // pre-swizzled global chunk
            int wub = ((u & ~63) << 3);                           // wave-uniform LDS elem offset
            size_t offA = (size_t)(m0 + row) * Kdim + k0 + kc;
            size_t offB = (size_t)(n0 + row) * Kdim + k0 + kc;
            GLD16(Ah  + offA, &lds[buf][0][wub]);
            GLD16(Al  + offA, &lds[buf][1][wub]);
            GLD16(BTh + offB, &lds[buf][2][wub]);
            GLD16(BTl + offB, &lds[buf][3][wub]);
        }
    };

    v4f acc[4][4] = {};
    stage(0, 0);                       // 8 GLD16 in flight
    int cur = 0;
    for (int kt = 0; kt < nk; ++kt) {
        __builtin_amdgcn_s_barrier();  // B1: all waves done reading buf[cur^1] (iter kt-1)
        if (kt + 1 < nk) {
            stage(cur ^ 1, (kt + 1) << 5);                        // outstanding: 16
            asm volatile("s_waitcnt vmcnt(8)" ::: "memory");      // my stage(kt) landed
        } else {
            asm volatile("s_waitcnt vmcnt(0)" ::: "memory");
        }
        __builtin_amdgcn_s_barrier();  // B2: everyone's stage(kt) landed
        __builtin_amdgcn_sched_barrier(0);
        v8s afh[4], afl[4], bfh[4], bfl[4];
        #pragma unroll
        for (int f = 0; f < 4; ++f) {
            int ra = (mw + f * 16 + l15) * 32 + lke;
            int rb = (nw + f * 16 + l15) * 32 + lke;
            afh[f] = *(const v8s*)&lds[cur][0][ra];
            afl[f] = *(const v8s*)&lds[cur][1][ra];
            bfh[f] = *(const v8s*)&lds[cur][2][rb];
            bfl[f] = *(const v8s*)&lds[cur][3][rb];
        }
        __builtin_amdgcn_s_setprio(1);
        #pragma unroll
        for (int i = 0; i < 4; ++i)
            #pragma unroll
            for (int j = 0; j < 4; ++j) {
                acc[i][j] = __builtin_amdgcn_mfma_f32_16x16x32_bf16(afh[i], bfh[j], acc[i][j], 0, 0, 0);
                acc[i][j] = __builtin_amdgcn_mfma_f32_16x16x32_bf16(afl[i], bfh[j], acc[i][j], 0, 0, 0);
                acc[i][j] = __builtin_amdgcn_mfma_f32_16x16x32_bf16(afh[i], bfl[j], acc[i][j], 0, 0, 0);
            }
        __builtin_amdgcn_s_setprio(0);
        cur ^= 1;
    }
    #pragma unroll
    for (int i = 0; i < 4; ++i) {
        int row0 = m0 + mw + i * 16 + lk8 * 4;   // C/D: col=lane&15, row=(lane>>4)*4+reg (m89)
        #pragma unroll
        for (int j = 0; j < 4; ++j) {
            int col = n0 + nw + j * 16 + l15;
            float bv = bias[col];
            int ct = 2;                            // 2 = identity
            if (actMode) {
                if (col < NKQV_) ct = (col % 320) >> 6;            // 0 k,1 q,2 v,3 b,4 g
                else { int m12 = (col - NKQV_) % 12; ct = (m12 < 8) ? 0 : 3; }  // p1/p2 relu, p3 sigm
            }
            #pragma unroll
            for (int rg = 0; rg < 4; ++rg) {
                float y = acc[i][j][rg] + bv;
                if (ct == 0 || ct == 1) y = fmaxf(y, 0.f);
                else if (ct >= 3) y = sigm(y);
                Yo[(size_t)(row0 + rg) * ldy + col] = y;
            }
        }
    }
}

// ---- scan phase 1: per (chunk,head) local scan from zero + decay products ----
// Y1 is PRE-ACTIVATED: k->relu, q->relu, v->id, b->sigm, g->sigm, p1/p2->relu, p3->sigm.
// CL record (49 vectors of 64 floats): [0,32)=kc[r*4+e], [32,40)=vc[r], [40,44)=sc[e], [44,48)=Pg[e], 48=Pb
__global__ __launch_bounds__(64) void scan_p1(const float* __restrict__ Y1, const float* __restrict__ OC,
                                              const int* __restrict__ term, float* __restrict__ CL) {
    const int b = blockIdx.x, c = b / H_, h = b % H_, lane = threadIdx.x;
    float kc[R_][ETA_] = {}, vc[R_] = {}, sc[ETA_] = {};
    float Pg[ETA_] = {1.f, 1.f, 1.f, 1.f}, Pb = 1.f;
    for (int t = c * LC_; t < c * LC_ + LC_; ++t) {
        const float* row = Y1 + (size_t)t * N1_;
        const float* bh = row + h * 320;
        float rk = bh[lane], vv = bh[128 + lane], sb = bh[192 + lane], sg = bh[256 + lane];
        const float* pp = row + NKQV_ + h * 12;
        float nt = 1.f - (float)term[t];
        float vals = vv * sb, dbv = (1.f - sb) * nt;
        float occ[R_];
        #pragma unroll
        for (int r = 0; r < R_; ++r) occ[r] = OC[t * R_ + r];
        #pragma unroll
        for (int e = 0; e < ETA_; ++e) {
            float gam = sg * pp[8 + e];
            float kg = rk * pp[e] * gam;
            float dgv = (1.f - gam) * nt;
            sc[e] = dgv * sc[e] + kg;
            Pg[e] *= dgv;
            #pragma unroll
            for (int r = 0; r < R_; ++r) kc[r][e] = dgv * kc[r][e] + kg * occ[r];
        }
        Pb *= dbv;
        #pragma unroll
        for (int r = 0; r < R_; ++r) vc[r] = dbv * vc[r] + vals * occ[r];
    }
    float* out = CL + (size_t)b * 49 * 64;
    #pragma unroll
    for (int r = 0; r < R_; ++r)
        #pragma unroll
        for (int e = 0; e < ETA_; ++e) out[(r * 4 + e) * 64 + lane] = kc[r][e];
    #pragma unroll
    for (int r = 0; r < R_; ++r) out[(32 + r) * 64 + lane] = vc[r];
    #pragma unroll
    for (int e = 0; e < ETA_; ++e) out[(40 + e) * 64 + lane] = sc[e];
    #pragma unroll
    for (int e = 0; e < ETA_; ++e) out[(44 + e) * 64 + lane] = Pg[e];
    out[48 * 64 + lane] = Pb;
}

// ---- scan phase 2 (element-parallel): each thread owns one (h, vec, lane) state scalar ----
__global__ __launch_bounds__(256) void scan_comb(const float* __restrict__ CL, float* __restrict__ CI,
                                                 const float* __restrict__ TK, const float* __restrict__ TV,
                                                 const float* __restrict__ SP) {
    const int gid = blockIdx.x * 256 + threadIdx.x;
    const int lane = gid & 63;
    const int hv = gid >> 6;          // 0..351
    const int h = hv / 44;
    const int v = hv % 44;
    float x;
    int dvec;
    if (v < 32) {
        int r = v >> 2, e = v & 3;
        x = TK[((size_t)r * H_ + h) * E_ + lane * 4 + e];
        dvec = 44 + e;
    } else if (v < 40) {
        int r = v - 32;
        x = TV[((size_t)r * H_ + h) * DH_ + lane];
        dvec = 48;
    } else {
        int e = v - 40;
        x = SP[(size_t)h * E_ + lane * 4 + e];
        dvec = 44 + e;
    }
    const float* clb = CL + (size_t)h * 49 * 64 + (size_t)v * 64 + lane;
    const float* dcb = CL + (size_t)h * 49 * 64 + (size_t)dvec * 64 + lane;
    float* cib = CI + (size_t)h * 44 * 64 + (size_t)v * 64 + lane;
    const size_t sCL = (size_t)H_ * 49 * 64;
    const size_t sCI = (size_t)H_ * 44 * 64;
    #pragma unroll 8
    for (int c = 0; c < NC_; ++c) {
        cib[(size_t)c * sCI] = x;
        float cl = clb[(size_t)c * sCL];
        float d  = dcb[(size_t)c * sCL];
        x = fmaf(d, x, cl);
    }
}

// ---- scan phase 3: re-scan with carry-in, emit attn (bf16 hi/lo, S x 512) ----
__global__ __launch_bounds__(64) void scan_p3(const float* __restrict__ Y1, const float* __restrict__ OC,
                                              const int* __restrict__ term, const float* __restrict__ CI,
                                              u16* __restrict__ attnH, u16* __restrict__ attnL) {
    const int b = blockIdx.x, c = b / H_, h = b % H_, lane = threadIdx.x;
    float kc[R_][ETA_], vc[R_], sc[ETA_];
    const float* ci = CI + (size_t)b * 44 * 64;
    #pragma unroll
    for (int r = 0; r < R_; ++r)
        #pragma unroll
        for (int e = 0; e < ETA_; ++e) kc[r][e] = ci[(r * 4 + e) * 64 + lane];
    #pragma unroll
    for (int r = 0; r < R_; ++r) vc[r] = ci[(32 + r) * 64 + lane];
    #pragma unroll
    for (int e = 0; e < ETA_; ++e) sc[e] = ci[(40 + e) * 64 + lane];
    for (int t = c * LC_; t < c * LC_ + LC_; ++t) {
        const float* row = Y1 + (size_t)t * N1_;
        const float* bh = row + h * 320;
        float rk = bh[lane], rq = bh[64 + lane], vv = bh[128 + lane], sb = bh[192 + lane], sg = bh[256 + lane];
        const float* pp = row + NKQV_ + h * 12;
        float nt = 1.f - (float)term[t];
        float vals = vv * sb, dbv = (1.f - sb) * nt;
        float occ[R_];
        #pragma unroll
        for (int r = 0; r < R_; ++r) occ[r] = OC[t * R_ + r];
        float qe[ETA_];
        #pragma unroll
        for (int e = 0; e < ETA_; ++e) {
            float gam = sg * pp[8 + e];
            float kg = rk * pp[e] * gam;
            float dgv = (1.f - gam) * nt;
            qe[e] = rq * pp[4 + e];
            sc[e] = dgv * sc[e] + kg;
            #pragma unroll
            for (int r = 0; r < R_; ++r) kc[r][e] = dgv * kc[r][e] + kg * occ[r];
        }
        #pragma unroll
        for (int r = 0; r < R_; ++r) vc[r] = dbv * vc[r] + vals * occ[r];
        float kdq[R_], nrm = 0.f;
        #pragma unroll
        for (int r = 0; r < R_; ++r) {
            float s = 0.f;
            #pragma unroll
            for (int e = 0; e < ETA_; ++e) s += kc[r][e] * qe[e];
            kdq[r] = s;
        }
        #pragma unroll
        for (int e = 0; e < ETA_; ++e) nrm += sc[e] * qe[e];
        #pragma unroll
        for (int m = 1; m < 64; m <<= 1) {
            #pragma unroll
            for (int r = 0; r < R_; ++r) kdq[r] += __shfl_xor(kdq[r], m);
            nrm += __shfl_xor(nrm, m);
        }
        float kv = 0.f;
        #pragma unroll
        for (int r = 0; r < R_; ++r) kv += vc[r] * kdq[r];
        float at = kv / (2.f * R_ * nrm + 1e-5f);
        size_t oi = (size_t)t * (H_ * DH_) + h * DH_ + lane;
        u16 hi = f2bf(at);
        attnH[oi] = hi;
        attnL[oi] = f2bf(at - bf2f(hi));
    }
}

extern "C" void kernel_launch(void* const* d_in, const int* in_sizes, int n_in,
                              void* d_out, int out_size, void* d_ws, size_t ws_size,
                              hipStream_t stream) {
    const float* inputs = (const float*)d_in[0];
    const int*   term   = (const int*)d_in[1];
    const float* Wk     = (const float*)d_in[2];
    const float* bk     = (const float*)d_in[3];
    const float* Wp     = (const float*)d_in[4];
    const float* bp     = (const float*)d_in[5];
    const float* Wproj  = (const float*)d_in[6];
    const float* bproj  = (const float*)d_in[7];
    const float* TK     = (const float*)d_in[8];
    const float* TV     = (const float*)d_in[9];
    const float* SP     = (const float*)d_in[10];
    const float* tick   = (const float*)d_in[11];
    float* out = (float*)d_out;

    char* w = (char*)d_ws;
    u16* AbfH   = (u16*)w;  w += (size_t)S_ * D_ * 2;          // 8 MB
    u16* AbfL   = (u16*)w;  w += (size_t)S_ * D_ * 2;          // 8 MB
    u16* BTh    = (u16*)w;  w += (size_t)N1_ * D_ * 2;         // 5.5 MB  [n][k]
    u16* BTl    = (u16*)w;  w += (size_t)N1_ * D_ * 2;         // 5.5 MB
    u16* WpTh   = (u16*)w;  w += (size_t)D_ * 512 * 2;         // 1 MB    [n][k]
    u16* WpTl   = (u16*)w;  w += (size_t)D_ * 512 * 2;         // 1 MB
    u16* attnH  = (u16*)w;  w += (size_t)S_ * 512 * 2;         // 4 MB
    u16* attnL  = (u16*)w;  w += (size_t)S_ * 512 * 2;         // 4 MB
    float* biasb = (float*)w; w += (size_t)N1_ * 4;
    float* Y1   = (float*)w; w += (size_t)S_ * N1_ * 4;        // 44 MB
    float* OC   = (float*)w; w += (size_t)S_ * R_ * 4;
    float* CL   = (float*)w; w += (size_t)NC_ * H_ * 49 * 64 * 4;  // 12.8 MB
    float* CI   = (float*)w; w += (size_t)NC_ * H_ * 44 * 64 * 4;  // 11.5 MB

    prep_all<<<PB_TOTAL, 256, 0, stream>>>(inputs, Wk, Wp, Wproj, bk, bp, tick,
                                           AbfH, AbfL, BTh, BTl, WpTh, WpTl, biasb, OC);
    gemm_x3_pipe<<<dim3(N1_ / 128, S_ / 128), 256, 0, stream>>>(AbfH, AbfL, BTh, BTl, biasb, Y1, N1_, D_, 1);
    scan_p1<<<NC_ * H_, 64, 0, stream>>>(Y1, OC, term, CL);
    scan_comb<<<(H_ * 44 * 64) / 256, 256, 0, stream>>>(CL, CI, TK, TV, SP);
    scan_p3<<<NC_ * H_, 64, 0, stream>>>(Y1, OC, term, CI, attnH, attnL);
    gemm_x3_pipe<<<dim3(1024 / 128, S_ / 128), 256, 0, stream>>>(attnH, attnL, WpTh, WpTl, bproj, out, D_, 512, 0);
}

// Round 6
// 171.229 us; speedup vs baseline: 2.5577x; 1.2016x over previous
//
#include <hip/hip_runtime.h>
#include <hip/hip_bf16.h>

// ---- problem constants ----
#define S_    4096
#define D_    1024
#define H_    8
#define DH_   64
#define ETA_  4
#define R_    8
#define E_    256
#define NC_   128          // scan chunks
#define LC_   (S_/NC_)     // 32 steps per chunk
#define N1_   2688         // padded N for GEMM1 (21*128)
#define NKQV_ 2560
#define NP_   96
#define PIF   3.14159265358979323846

// prep_all block-range boundaries
#define PB_CVT    2048                 // inputs fp32->fp16 hi/lo split
#define PB_TRWK   (PB_CVT + 640)       // W_kqv transpose (16 k-tiles x 40 n-tiles)
#define PB_TRWP   (PB_TRWK + 32)       // W_p transpose (16 x 2)
#define PB_TRWPJ  (PB_TRWP + 128)      // W_proj transpose (8 x 16)
#define PB_OC     (PB_TRWPJ + 128)     // oscillator table
#define PB_BIAS   (PB_OC + 11)         // bias1
#define PB_TOTAL  PB_BIAS

typedef unsigned short u16;
typedef unsigned int   u32;
typedef _Float16 v8h __attribute__((ext_vector_type(8)));
typedef float v4f __attribute__((ext_vector_type(4)));

__device__ __forceinline__ u16 f2h(float f) {
    _Float16 h = (_Float16)f;                 // RTN
    return __builtin_bit_cast(unsigned short, h);
}
__device__ __forceinline__ float h2f(u16 u) {
    return (float)__builtin_bit_cast(_Float16, u);
}
__device__ __forceinline__ float sigm(float x) { return 1.f / (1.f + expf(-x)); }

// async global->LDS, 16 B per lane; LDS dest = wave-uniform base + lane*16
#define GLD16(gp, lp) __builtin_amdgcn_global_load_lds( \
    (const __attribute__((address_space(1))) u32*)(const void*)(gp), \
    (__attribute__((address_space(3))) u32*)(void*)(lp), 16, 0, 0)

// ---- transpose 64x64 tile -> fp16 (hi only) ----
__device__ __forceinline__ void tr64h(float (*tile)[65], const float* __restrict__ src, int K, int Nsrc,
                                      u16* __restrict__ dH, int rowOff, int k0, int n0, int t) {
    const int cc = t & 63, rr = t >> 6;
    #pragma unroll
    for (int i = 0; i < 16; ++i) {
        int kk = rr * 16 + i;
        tile[kk][cc] = (n0 + cc < Nsrc) ? src[(size_t)(k0 + kk) * Nsrc + n0 + cc] : 0.f;
    }
    __syncthreads();
    #pragma unroll
    for (int i = 0; i < 16; ++i) {
        int nn = rr * 16 + i;
        dH[(size_t)(rowOff + n0 + nn) * K + k0 + cc] = f2h(tile[cc][nn]);
    }
}

// ---- fused prep: cvt inputs (hi/lo), 3 transposes (hi), oscillator table, bias ----
__global__ __launch_bounds__(256) void prep_all(const float* __restrict__ inputs,
                                                const float* __restrict__ Wk, const float* __restrict__ Wp,
                                                const float* __restrict__ Wproj,
                                                const float* __restrict__ bk, const float* __restrict__ bp,
                                                const float* __restrict__ tick,
                                                u16* __restrict__ AbfH, u16* __restrict__ AbfL,
                                                u16* __restrict__ BTh, u16* __restrict__ WpTh,
                                                float* __restrict__ biasb, float* __restrict__ OC) {
    __shared__ float tile[64][65];
    const int b = blockIdx.x, t = threadIdx.x;
    if (b < PB_CVT) {
        int i = b * 256 + t;                       // 8 elems per thread
        const float4* xp = (const float4*)inputs;
        float4 a = xp[2 * i], bb = xp[2 * i + 1];
        float v[8] = {a.x, a.y, a.z, a.w, bb.x, bb.y, bb.z, bb.w};
        unsigned hh[8], ll[8];
        #pragma unroll
        for (int j = 0; j < 8; ++j) {
            u16 h = f2h(v[j]);
            hh[j] = h;
            ll[j] = f2h(v[j] - h2f(h));
        }
        uint4 rh, rl;
        rh.x = hh[0] | (hh[1] << 16); rh.y = hh[2] | (hh[3] << 16);
        rh.z = hh[4] | (hh[5] << 16); rh.w = hh[6] | (hh[7] << 16);
        rl.x = ll[0] | (ll[1] << 16); rl.y = ll[2] | (ll[3] << 16);
        rl.z = ll[4] | (ll[5] << 16); rl.w = ll[6] | (ll[7] << 16);
        ((uint4*)AbfH)[i] = rh;
        ((uint4*)AbfL)[i] = rl;
    } else if (b < PB_TRWK) {
        int i = b - PB_CVT;
        tr64h(tile, Wk, D_, NKQV_, BTh, 0, (i % 16) * 64, (i / 16) * 64, t);
    } else if (b < PB_TRWP) {
        int i = b - PB_TRWK;
        tr64h(tile, Wp, D_, NP_, BTh, NKQV_, (i % 16) * 64, (i / 16) * 64, t);
    } else if (b < PB_TRWPJ) {
        int i = b - PB_TRWP;
        tr64h(tile, Wproj, 512, D_, WpTh, 0, (i % 8) * 64, (i / 8) * 64, t);
    } else if (b < PB_OC) {
        int idx = (b - PB_TRWPJ) * 256 + t;
        int tt = idx / R_, r = idx % R_;
        float start = (float)(-PIF), stop = (float)PIF;
        float step = __fdiv_rn(__fsub_rn(stop, start), 7.0f);
        float om = __fadd_rn(start, __fmul_rn((float)r, step));
        float tk = __fadd_rn(tick[0], (float)(tt + 1));
        OC[idx] = cosf(__fmul_rn(tk, om));
    } else {
        int n = (b - PB_OC) * 256 + t;
        if (n < N1_)
            biasb[n] = n < NKQV_ ? bk[n] : (n < NKQV_ + NP_ ? bp[n - NKQV_] : 0.f);
    }
}

// ---- split-fp16 x2 MFMA GEMM: Y = (Ah+Al)*Bh + bias  (B lo dropped; err ~2^-11 one-sided) ----
// A:[M][K] fp16-bits hi/lo row-major. BT:[N][K] fp16 hi row-major. 128x128 tile, 4 waves, BK=32.
// R3-proven schedule: barrier -> prefetch stage(kt+1) -> ds_read + 32 MFMA on buf[kt].
// actMode=1: GEMM1 column-typed activation fused into epilogue.
__global__ __launch_bounds__(256, 3) void gemm_x2_pipe(const u16* __restrict__ Ah, const u16* __restrict__ Al,
                                                       const u16* __restrict__ BTh,
                                                       const float* __restrict__ bias,
                                                       float* __restrict__ Yo, int ldy, int Kdim, int actMode) {
    __shared__ __align__(16) u16 lds[2][3][4096];   // 2 buf x {AH,AL,BH} x [128 rows][32 k] = 48 KB
    const int tid = threadIdx.x, lane = tid & 63, w = tid >> 6;
    const int mw = (w >> 1) * 64, nw = (w & 1) * 64;
    const int l15 = lane & 15, lk8 = lane >> 4;
    const int lke = (lk8 ^ (l15 & 3) ^ ((l15 >> 2) & 3)) * 8;   // swizzled k-slot for frag reads
    // XCD-aware block swizzle (total blocks % 8 == 0)
    const int gx = gridDim.x;
    const int nb = gx * gridDim.y;
    const int orig = blockIdx.y * gx + blockIdx.x;
    const int per = nb >> 3;
    const int swz = (orig & 7) * per + (orig >> 3);
    const int m0 = (swz / gx) * 128, n0 = (swz % gx) * 128;
    const int nk = Kdim >> 5;

    auto stage = [&](int buf, int k0) {
        #pragma unroll
        for (int c = 0; c < 2; ++c) {
            int u = tid + (c << 8);                               // 0..511 chunk index
            int row = u >> 2, s = u & 3;
            int kc = ((s ^ (row & 3) ^ ((row >> 2) & 3)) << 3);   // pre-swizzled global chunk
            int wub = ((u & ~63) << 3);                           // wave-uniform LDS elem offset
            size_t offA = (size_t)(m0 + row) * Kdim + k0 + kc;
            size_t offB = (size_t)(n0 + row) * Kdim + k0 + kc;
            GLD16(Ah  + offA, &lds[buf][0][wub]);
            GLD16(Al  + offA, &lds[buf][1][wub]);
            GLD16(BTh + offB, &lds[buf][2][wub]);
        }
    };

    v4f acc[4][4] = {};
    stage(0, 0);
    int cur = 0;
    for (int kt = 0; kt < nk; ++kt) {
        __syncthreads();                      // drains vmcnt: buf[cur] staged; prev frag reads done
        if (kt + 1 < nk) stage(cur ^ 1, (kt + 1) << 5);
        v8h afh[4], afl[4], bfh[4];
        #pragma unroll
        for (int f = 0; f < 4; ++f) {
            int ra = (mw + f * 16 + l15) * 32 + lke;
            int rb = (nw + f * 16 + l15) * 32 + lke;
            afh[f] = *(const v8h*)&lds[cur][0][ra];
            afl[f] = *(const v8h*)&lds[cur][1][ra];
            bfh[f] = *(const v8h*)&lds[cur][2][rb];
        }
        #pragma unroll
        for (int i = 0; i < 4; ++i)
            #pragma unroll
            for (int j = 0; j < 4; ++j) {
                acc[i][j] = __builtin_amdgcn_mfma_f32_16x16x32_f16(afh[i], bfh[j], acc[i][j], 0, 0, 0);
                acc[i][j] = __builtin_amdgcn_mfma_f32_16x16x32_f16(afl[i], bfh[j], acc[i][j], 0, 0, 0);
            }
        cur ^= 1;
    }
    #pragma unroll
    for (int i = 0; i < 4; ++i) {
        int row0 = m0 + mw + i * 16 + lk8 * 4;   // C/D: col=lane&15, row=(lane>>4)*4+reg (m89)
        #pragma unroll
        for (int j = 0; j < 4; ++j) {
            int col = n0 + nw + j * 16 + l15;
            float bv = bias[col];
            int ct = 2;                            // 2 = identity
            if (actMode) {
                if (col < NKQV_) ct = (col % 320) >> 6;            // 0 k,1 q,2 v,3 b,4 g
                else { int m12 = (col - NKQV_) % 12; ct = (m12 < 8) ? 0 : 3; }  // p1/p2 relu, p3 sigm
            }
            #pragma unroll
            for (int rg = 0; rg < 4; ++rg) {
                float y = acc[i][j][rg] + bv;
                if (ct == 0 || ct == 1) y = fmaxf(y, 0.f);
                else if (ct >= 3) y = sigm(y);
                Yo[(size_t)(row0 + rg) * ldy + col] = y;
            }
        }
    }
}

// ---- scan phase 1: per (chunk,head) local scan from zero + decay products ----
// Y1 is PRE-ACTIVATED: k->relu, q->relu, v->id, b->sigm, g->sigm, p1/p2->relu, p3->sigm.
// CL record (49 vectors of 64 floats): [0,32)=kc[r*4+e], [32,40)=vc[r], [40,44)=sc[e], [44,48)=Pg[e], 48=Pb
__global__ __launch_bounds__(64) void scan_p1(const float* __restrict__ Y1, const float* __restrict__ OC,
                                              const int* __restrict__ term, float* __restrict__ CL) {
    const int b = blockIdx.x, c = b / H_, h = b % H_, lane = threadIdx.x;
    float kc[R_][ETA_] = {}, vc[R_] = {}, sc[ETA_] = {};
    float Pg[ETA_] = {1.f, 1.f, 1.f, 1.f}, Pb = 1.f;
    for (int t = c * LC_; t < c * LC_ + LC_; ++t) {
        const float* row = Y1 + (size_t)t * N1_;
        const float* bh = row + h * 320;
        float rk = bh[lane], vv = bh[128 + lane], sb = bh[192 + lane], sg = bh[256 + lane];
        const float* pp = row + NKQV_ + h * 12;
        float nt = 1.f - (float)term[t];
        float vals = vv * sb, dbv = (1.f - sb) * nt;
        float occ[R_];
        #pragma unroll
        for (int r = 0; r < R_; ++r) occ[r] = OC[t * R_ + r];
        #pragma unroll
        for (int e = 0; e < ETA_; ++e) {
            float gam = sg * pp[8 + e];
            float kg = rk * pp[e] * gam;
            float dgv = (1.f - gam) * nt;
            sc[e] = dgv * sc[e] + kg;
            Pg[e] *= dgv;
            #pragma unroll
            for (int r = 0; r < R_; ++r) kc[r][e] = dgv * kc[r][e] + kg * occ[r];
        }
        Pb *= dbv;
        #pragma unroll
        for (int r = 0; r < R_; ++r) vc[r] = dbv * vc[r] + vals * occ[r];
    }
    float* out = CL + (size_t)b * 49 * 64;
    #pragma unroll
    for (int r = 0; r < R_; ++r)
        #pragma unroll
        for (int e = 0; e < ETA_; ++e) out[(r * 4 + e) * 64 + lane] = kc[r][e];
    #pragma unroll
    for (int r = 0; r < R_; ++r) out[(32 + r) * 64 + lane] = vc[r];
    #pragma unroll
    for (int e = 0; e < ETA_; ++e) out[(40 + e) * 64 + lane] = sc[e];
    #pragma unroll
    for (int e = 0; e < ETA_; ++e) out[(44 + e) * 64 + lane] = Pg[e];
    out[48 * 64 + lane] = Pb;
}

// ---- scan phase 2 (element-parallel): each thread owns one (h, vec, lane) state scalar ----
__global__ __launch_bounds__(256) void scan_comb(const float* __restrict__ CL, float* __restrict__ CI,
                                                 const float* __restrict__ TK, const float* __restrict__ TV,
                                                 const float* __restrict__ SP) {
    const int gid = blockIdx.x * 256 + threadIdx.x;
    const int lane = gid & 63;
    const int hv = gid >> 6;          // 0..351
    const int h = hv / 44;
    const int v = hv % 44;
    float x;
    int dvec;
    if (v < 32) {
        int r = v >> 2, e = v & 3;
        x = TK[((size_t)r * H_ + h) * E_ + lane * 4 + e];
        dvec = 44 + e;
    } else if (v < 40) {
        int r = v - 32;
        x = TV[((size_t)r * H_ + h) * DH_ + lane];
        dvec = 48;
    } else {
        int e = v - 40;
        x = SP[(size_t)h * E_ + lane * 4 + e];
        dvec = 44 + e;
    }
    const float* clb = CL + (size_t)h * 49 * 64 + (size_t)v * 64 + lane;
    const float* dcb = CL + (size_t)h * 49 * 64 + (size_t)dvec * 64 + lane;
    float* cib = CI + (size_t)h * 44 * 64 + (size_t)v * 64 + lane;
    const size_t sCL = (size_t)H_ * 49 * 64;
    const size_t sCI = (size_t)H_ * 44 * 64;
    #pragma unroll 8
    for (int c = 0; c < NC_; ++c) {
        cib[(size_t)c * sCI] = x;
        float cl = clb[(size_t)c * sCL];
        float d  = dcb[(size_t)c * sCL];
        x = fmaf(d, x, cl);
    }
}

// ---- scan phase 3: re-scan with carry-in, emit attn (fp16 hi/lo, S x 512) ----
__global__ __launch_bounds__(64) void scan_p3(const float* __restrict__ Y1, const float* __restrict__ OC,
                                              const int* __restrict__ term, const float* __restrict__ CI,
                                              u16* __restrict__ attnH, u16* __restrict__ attnL) {
    const int b = blockIdx.x, c = b / H_, h = b % H_, lane = threadIdx.x;
    float kc[R_][ETA_], vc[R_], sc[ETA_];
    const float* ci = CI + (size_t)b * 44 * 64;
    #pragma unroll
    for (int r = 0; r < R_; ++r)
        #pragma unroll
        for (int e = 0; e < ETA_; ++e) kc[r][e] = ci[(r * 4 + e) * 64 + lane];
    #pragma unroll
    for (int r = 0; r < R_; ++r) vc[r] = ci[(32 + r) * 64 + lane];
    #pragma unroll
    for (int e = 0; e < ETA_; ++e) sc[e] = ci[(40 + e) * 64 + lane];
    for (int t = c * LC_; t < c * LC_ + LC_; ++t) {
        const float* row = Y1 + (size_t)t * N1_;
        const float* bh = row + h * 320;
        float rk = bh[lane], rq = bh[64 + lane], vv = bh[128 + lane], sb = bh[192 + lane], sg = bh[256 + lane];
        const float* pp = row + NKQV_ + h * 12;
        float nt = 1.f - (float)term[t];
        float vals = vv * sb, dbv = (1.f - sb) * nt;
        float occ[R_];
        #pragma unroll
        for (int r = 0; r < R_; ++r) occ[r] = OC[t * R_ + r];
        float qe[ETA_];
        #pragma unroll
        for (int e = 0; e < ETA_; ++e) {
            float gam = sg * pp[8 + e];
            float kg = rk * pp[e] * gam;
            float dgv = (1.f - gam) * nt;
            qe[e] = rq * pp[4 + e];
            sc[e] = dgv * sc[e] + kg;
            #pragma unroll
            for (int r = 0; r < R_; ++r) kc[r][e] = dgv * kc[r][e] + kg * occ[r];
        }
        #pragma unroll
        for (int r = 0; r < R_; ++r) vc[r] = dbv * vc[r] + vals * occ[r];
        float kdq[R_], nrm = 0.f;
        #pragma unroll
        for (int r = 0; r < R_; ++r) {
            float s = 0.f;
            #pragma unroll
            for (int e = 0; e < ETA_; ++e) s += kc[r][e] * qe[e];
            kdq[r] = s;
        }
        #pragma unroll
        for (int e = 0; e < ETA_; ++e) nrm += sc[e] * qe[e];
        #pragma unroll
        for (int m = 1; m < 64; m <<= 1) {
            #pragma unroll
            for (int r = 0; r < R_; ++r) kdq[r] += __shfl_xor(kdq[r], m);
            nrm += __shfl_xor(nrm, m);
        }
        float kv = 0.f;
        #pragma unroll
        for (int r = 0; r < R_; ++r) kv += vc[r] * kdq[r];
        float at = kv / (2.f * R_ * nrm + 1e-5f);
        size_t oi = (size_t)t * (H_ * DH_) + h * DH_ + lane;
        u16 hi = f2h(at);
        attnH[oi] = hi;
        attnL[oi] = f2h(at - h2f(hi));
    }
}

extern "C" void kernel_launch(void* const* d_in, const int* in_sizes, int n_in,
                              void* d_out, int out_size, void* d_ws, size_t ws_size,
                              hipStream_t stream) {
    const float* inputs = (const float*)d_in[0];
    const int*   term   = (const int*)d_in[1];
    const float* Wk     = (const float*)d_in[2];
    const float* bk     = (const float*)d_in[3];
    const float* Wp     = (const float*)d_in[4];
    const float* bp     = (const float*)d_in[5];
    const float* Wproj  = (const float*)d_in[6];
    const float* bproj  = (const float*)d_in[7];
    const float* TK     = (const float*)d_in[8];
    const float* TV     = (const float*)d_in[9];
    const float* SP     = (const float*)d_in[10];
    const float* tick   = (const float*)d_in[11];
    float* out = (float*)d_out;

    char* w = (char*)d_ws;
    u16* AbfH   = (u16*)w;  w += (size_t)S_ * D_ * 2;          // 8 MB
    u16* AbfL   = (u16*)w;  w += (size_t)S_ * D_ * 2;          // 8 MB
    u16* BTh    = (u16*)w;  w += (size_t)N1_ * D_ * 2;         // 5.5 MB  [n][k]
    u16* WpTh   = (u16*)w;  w += (size_t)D_ * 512 * 2;         // 1 MB    [n][k]
    u16* attnH  = (u16*)w;  w += (size_t)S_ * 512 * 2;         // 4 MB
    u16* attnL  = (u16*)w;  w += (size_t)S_ * 512 * 2;         // 4 MB
    float* biasb = (float*)w; w += (size_t)N1_ * 4;
    float* Y1   = (float*)w; w += (size_t)S_ * N1_ * 4;        // 44 MB
    float* OC   = (float*)w; w += (size_t)S_ * R_ * 4;
    float* CL   = (float*)w; w += (size_t)NC_ * H_ * 49 * 64 * 4;  // 12.8 MB
    float* CI   = (float*)w; w += (size_t)NC_ * H_ * 44 * 64 * 4;  // 11.5 MB

    prep_all<<<PB_TOTAL, 256, 0, stream>>>(inputs, Wk, Wp, Wproj, bk, bp, tick,
                                           AbfH, AbfL, BTh, WpTh, biasb, OC);
    gemm_x2_pipe<<<dim3(N1_ / 128, S_ / 128), 256, 0, stream>>>(AbfH, AbfL, BTh, biasb, Y1, N1_, D_, 1);
    scan_p1<<<NC_ * H_, 64, 0, stream>>>(Y1, OC, term, CL);
    scan_comb<<<(H_ * 44 * 64) / 256, 256, 0, stream>>>(CL, CI, TK, TV, SP);
    scan_p3<<<NC_ * H_, 64, 0, stream>>>(Y1, OC, term, CI, attnH, attnL);
    gemm_x2_pipe<<<dim3(1024 / 128, S_ / 128), 256, 0, stream>>>(attnH, attnL, WpTh, bproj, out, D_, 512, 0);
}

// Round 7
// 160.292 us; speedup vs baseline: 2.7322x; 1.0682x over previous
//
#include <hip/hip_runtime.h>
#include <hip/hip_bf16.h>

// ---- problem constants ----
#define S_    4096
#define D_    1024
#define H_    8
#define DH_   64
#define ETA_  4
#define R_    8
#define E_    256
#define NC_   256          // scan chunks (R6: 128 -> 256 for 2x scan TLP)
#define LC_   (S_/NC_)     // 16 steps per chunk
#define N1_   2688         // padded N for GEMM1 (21*128)
#define NKQV_ 2560
#define NP_   96
#define PIF   3.14159265358979323846

// prep_all block-range boundaries
#define PB_CVT    2048                 // inputs fp32->fp16 hi/lo split
#define PB_TRWK   (PB_CVT + 640)       // W_kqv transpose (16 k-tiles x 40 n-tiles)
#define PB_TRWP   (PB_TRWK + 32)       // W_p transpose (16 x 2)
#define PB_TRWPJ  (PB_TRWP + 128)      // W_proj transpose (8 x 16)
#define PB_OC     (PB_TRWPJ + 128)     // oscillator table
#define PB_BIAS   (PB_OC + 11)         // bias1
#define PB_TOTAL  PB_BIAS

typedef unsigned short u16;
typedef unsigned int   u32;
typedef _Float16 v8h __attribute__((ext_vector_type(8)));
typedef float v4f __attribute__((ext_vector_type(4)));

__device__ __forceinline__ u16 f2h(float f) {
    _Float16 h = (_Float16)f;                 // RTN
    return __builtin_bit_cast(unsigned short, h);
}
__device__ __forceinline__ float h2f(u16 u) {
    return (float)__builtin_bit_cast(_Float16, u);
}
__device__ __forceinline__ float sigm(float x) { return 1.f / (1.f + expf(-x)); }

// async global->LDS, 16 B per lane; LDS dest = wave-uniform base + lane*16
#define GLD16(gp, lp) __builtin_amdgcn_global_load_lds( \
    (const __attribute__((address_space(1))) u32*)(const void*)(gp), \
    (__attribute__((address_space(3))) u32*)(void*)(lp), 16, 0, 0)

// ---- transpose 64x64 tile -> fp16 (hi only) ----
__device__ __forceinline__ void tr64h(float (*tile)[65], const float* __restrict__ src, int K, int Nsrc,
                                      u16* __restrict__ dH, int rowOff, int k0, int n0, int t) {
    const int cc = t & 63, rr = t >> 6;
    #pragma unroll
    for (int i = 0; i < 16; ++i) {
        int kk = rr * 16 + i;
        tile[kk][cc] = (n0 + cc < Nsrc) ? src[(size_t)(k0 + kk) * Nsrc + n0 + cc] : 0.f;
    }
    __syncthreads();
    #pragma unroll
    for (int i = 0; i < 16; ++i) {
        int nn = rr * 16 + i;
        dH[(size_t)(rowOff + n0 + nn) * K + k0 + cc] = f2h(tile[cc][nn]);
    }
}

// ---- fused prep: cvt inputs (hi/lo), 3 transposes (hi), oscillator table, bias ----
__global__ __launch_bounds__(256) void prep_all(const float* __restrict__ inputs,
                                                const float* __restrict__ Wk, const float* __restrict__ Wp,
                                                const float* __restrict__ Wproj,
                                                const float* __restrict__ bk, const float* __restrict__ bp,
                                                const float* __restrict__ tick,
                                                u16* __restrict__ AbfH, u16* __restrict__ AbfL,
                                                u16* __restrict__ BTh, u16* __restrict__ WpTh,
                                                float* __restrict__ biasb, float* __restrict__ OC) {
    __shared__ float tile[64][65];
    const int b = blockIdx.x, t = threadIdx.x;
    if (b < PB_CVT) {
        int i = b * 256 + t;                       // 8 elems per thread
        const float4* xp = (const float4*)inputs;
        float4 a = xp[2 * i], bb = xp[2 * i + 1];
        float v[8] = {a.x, a.y, a.z, a.w, bb.x, bb.y, bb.z, bb.w};
        unsigned hh[8], ll[8];
        #pragma unroll
        for (int j = 0; j < 8; ++j) {
            u16 h = f2h(v[j]);
            hh[j] = h;
            ll[j] = f2h(v[j] - h2f(h));
        }
        uint4 rh, rl;
        rh.x = hh[0] | (hh[1] << 16); rh.y = hh[2] | (hh[3] << 16);
        rh.z = hh[4] | (hh[5] << 16); rh.w = hh[6] | (hh[7] << 16);
        rl.x = ll[0] | (ll[1] << 16); rl.y = ll[2] | (ll[3] << 16);
        rl.z = ll[4] | (ll[5] << 16); rl.w = ll[6] | (ll[7] << 16);
        ((uint4*)AbfH)[i] = rh;
        ((uint4*)AbfL)[i] = rl;
    } else if (b < PB_TRWK) {
        int i = b - PB_CVT;
        tr64h(tile, Wk, D_, NKQV_, BTh, 0, (i % 16) * 64, (i / 16) * 64, t);
    } else if (b < PB_TRWP) {
        int i = b - PB_TRWK;
        tr64h(tile, Wp, D_, NP_, BTh, NKQV_, (i % 16) * 64, (i / 16) * 64, t);
    } else if (b < PB_TRWPJ) {
        int i = b - PB_TRWP;
        tr64h(tile, Wproj, 512, D_, WpTh, 0, (i % 8) * 64, (i / 8) * 64, t);
    } else if (b < PB_OC) {
        int idx = (b - PB_TRWPJ) * 256 + t;
        int tt = idx / R_, r = idx % R_;
        float start = (float)(-PIF), stop = (float)PIF;
        float step = __fdiv_rn(__fsub_rn(stop, start), 7.0f);
        float om = __fadd_rn(start, __fmul_rn((float)r, step));
        float tk = __fadd_rn(tick[0], (float)(tt + 1));
        OC[idx] = cosf(__fmul_rn(tk, om));
    } else {
        int n = (b - PB_OC) * 256 + t;
        if (n < N1_)
            biasb[n] = n < NKQV_ ? bk[n] : (n < NKQV_ + NP_ ? bp[n - NKQV_] : 0.f);
    }
}

// ---- split-fp16 x2 MFMA GEMM: Y = (Ah+Al)*Bh + bias  (B lo dropped; err ~2^-11 one-sided) ----
// A:[M][K] fp16-bits hi/lo row-major. BT:[N][K] fp16 hi row-major. 128x128 tile, 4 waves, BK=32.
// Schedule: barrier -> prefetch stage(kt+1) -> ds_read + 32 MFMA on buf[kt].
// actMode=1: GEMM1 column-typed activation fused into epilogue.
__global__ __launch_bounds__(256, 3) void gemm_x2_pipe(const u16* __restrict__ Ah, const u16* __restrict__ Al,
                                                       const u16* __restrict__ BTh,
                                                       const float* __restrict__ bias,
                                                       float* __restrict__ Yo, int ldy, int Kdim, int actMode) {
    __shared__ __align__(16) u16 lds[2][3][4096];   // 2 buf x {AH,AL,BH} x [128 rows][32 k] = 48 KB
    const int tid = threadIdx.x, lane = tid & 63, w = tid >> 6;
    const int mw = (w >> 1) * 64, nw = (w & 1) * 64;
    const int l15 = lane & 15, lk8 = lane >> 4;
    const int lke = (lk8 ^ (l15 & 3) ^ ((l15 >> 2) & 3)) * 8;   // swizzled k-slot for frag reads
    // XCD-aware block swizzle (total blocks % 8 == 0)
    const int gx = gridDim.x;
    const int nb = gx * gridDim.y;
    const int orig = blockIdx.y * gx + blockIdx.x;
    const int per = nb >> 3;
    const int swz = (orig & 7) * per + (orig >> 3);
    const int m0 = (swz / gx) * 128, n0 = (swz % gx) * 128;
    const int nk = Kdim >> 5;

    auto stage = [&](int buf, int k0) {
        #pragma unroll
        for (int c = 0; c < 2; ++c) {
            int u = tid + (c << 8);                               // 0..511 chunk index
            int row = u >> 2, s = u & 3;
            int kc = ((s ^ (row & 3) ^ ((row >> 2) & 3)) << 3);   // pre-swizzled global chunk
            int wub = ((u & ~63) << 3);                           // wave-uniform LDS elem offset
            size_t offA = (size_t)(m0 + row) * Kdim + k0 + kc;
            size_t offB = (size_t)(n0 + row) * Kdim + k0 + kc;
            GLD16(Ah  + offA, &lds[buf][0][wub]);
            GLD16(Al  + offA, &lds[buf][1][wub]);
            GLD16(BTh + offB, &lds[buf][2][wub]);
        }
    };

    v4f acc[4][4] = {};
    stage(0, 0);
    int cur = 0;
    for (int kt = 0; kt < nk; ++kt) {
        __syncthreads();                      // drains vmcnt: buf[cur] staged; prev frag reads done
        if (kt + 1 < nk) stage(cur ^ 1, (kt + 1) << 5);
        v8h afh[4], afl[4], bfh[4];
        #pragma unroll
        for (int f = 0; f < 4; ++f) {
            int ra = (mw + f * 16 + l15) * 32 + lke;
            int rb = (nw + f * 16 + l15) * 32 + lke;
            afh[f] = *(const v8h*)&lds[cur][0][ra];
            afl[f] = *(const v8h*)&lds[cur][1][ra];
            bfh[f] = *(const v8h*)&lds[cur][2][rb];
        }
        #pragma unroll
        for (int i = 0; i < 4; ++i)
            #pragma unroll
            for (int j = 0; j < 4; ++j) {
                acc[i][j] = __builtin_amdgcn_mfma_f32_16x16x32_f16(afh[i], bfh[j], acc[i][j], 0, 0, 0);
                acc[i][j] = __builtin_amdgcn_mfma_f32_16x16x32_f16(afl[i], bfh[j], acc[i][j], 0, 0, 0);
            }
        cur ^= 1;
    }
    #pragma unroll
    for (int i = 0; i < 4; ++i) {
        int row0 = m0 + mw + i * 16 + lk8 * 4;   // C/D: col=lane&15, row=(lane>>4)*4+reg (m89)
        #pragma unroll
        for (int j = 0; j < 4; ++j) {
            int col = n0 + nw + j * 16 + l15;
            float bv = bias[col];
            int ct = 2;                            // 2 = identity
            if (actMode) {
                if (col < NKQV_) ct = (col % 320) >> 6;            // 0 k,1 q,2 v,3 b,4 g
                else { int m12 = (col - NKQV_) % 12; ct = (m12 < 8) ? 0 : 3; }  // p1/p2 relu, p3 sigm
            }
            #pragma unroll
            for (int rg = 0; rg < 4; ++rg) {
                float y = acc[i][j][rg] + bv;
                if (ct == 0 || ct == 1) y = fmaxf(y, 0.f);
                else if (ct >= 3) y = sigm(y);
                Yo[(size_t)(row0 + rg) * ldy + col] = y;
            }
        }
    }
}

// ---- scan phase 1: per (chunk,head) local scan from zero + decay products ----
// Y1 is PRE-ACTIVATED: k->relu, q->relu, v->id, b->sigm, g->sigm, p1/p2->relu, p3->sigm.
// CL record (49 vectors of 64 floats): [0,32)=kc[r*4+e], [32,40)=vc[r], [40,44)=sc[e], [44,48)=Pg[e], 48=Pb
__global__ __launch_bounds__(64) void scan_p1(const float* __restrict__ Y1, const float* __restrict__ OC,
                                              const int* __restrict__ term, float* __restrict__ CL) {
    const int b = blockIdx.x, c = b / H_, h = b % H_, lane = threadIdx.x;
    float kc[R_][ETA_] = {}, vc[R_] = {}, sc[ETA_] = {};
    float Pg[ETA_] = {1.f, 1.f, 1.f, 1.f}, Pb = 1.f;
    for (int t = c * LC_; t < c * LC_ + LC_; ++t) {
        const float* row = Y1 + (size_t)t * N1_;
        const float* bh = row + h * 320;
        float rk = bh[lane], vv = bh[128 + lane], sb = bh[192 + lane], sg = bh[256 + lane];
        const float* pp = row + NKQV_ + h * 12;
        float nt = 1.f - (float)term[t];
        float vals = vv * sb, dbv = (1.f - sb) * nt;
        float occ[R_];
        #pragma unroll
        for (int r = 0; r < R_; ++r) occ[r] = OC[t * R_ + r];
        #pragma unroll
        for (int e = 0; e < ETA_; ++e) {
            float gam = sg * pp[8 + e];
            float kg = rk * pp[e] * gam;
            float dgv = (1.f - gam) * nt;
            sc[e] = dgv * sc[e] + kg;
            Pg[e] *= dgv;
            #pragma unroll
            for (int r = 0; r < R_; ++r) kc[r][e] = dgv * kc[r][e] + kg * occ[r];
        }
        Pb *= dbv;
        #pragma unroll
        for (int r = 0; r < R_; ++r) vc[r] = dbv * vc[r] + vals * occ[r];
    }
    float* out = CL + (size_t)b * 49 * 64;
    #pragma unroll
    for (int r = 0; r < R_; ++r)
        #pragma unroll
        for (int e = 0; e < ETA_; ++e) out[(r * 4 + e) * 64 + lane] = kc[r][e];
    #pragma unroll
    for (int r = 0; r < R_; ++r) out[(32 + r) * 64 + lane] = vc[r];
    #pragma unroll
    for (int e = 0; e < ETA_; ++e) out[(40 + e) * 64 + lane] = sc[e];
    #pragma unroll
    for (int e = 0; e < ETA_; ++e) out[(44 + e) * 64 + lane] = Pg[e];
    out[48 * 64 + lane] = Pb;
}

// ---- scan phase 2 (element-parallel): 352 one-wave blocks; each thread owns one state scalar ----
__global__ __launch_bounds__(64) void scan_comb(const float* __restrict__ CL, float* __restrict__ CI,
                                                const float* __restrict__ TK, const float* __restrict__ TV,
                                                const float* __restrict__ SP) {
    const int gid = blockIdx.x * 64 + threadIdx.x;
    const int lane = gid & 63;
    const int hv = gid >> 6;          // 0..351
    const int h = hv / 44;
    const int v = hv % 44;
    float x;
    int dvec;
    if (v < 32) {
        int r = v >> 2, e = v & 3;
        x = TK[((size_t)r * H_ + h) * E_ + lane * 4 + e];
        dvec = 44 + e;
    } else if (v < 40) {
        int r = v - 32;
        x = TV[((size_t)r * H_ + h) * DH_ + lane];
        dvec = 48;
    } else {
        int e = v - 40;
        x = SP[(size_t)h * E_ + lane * 4 + e];
        dvec = 44 + e;
    }
    const float* clb = CL + (size_t)h * 49 * 64 + (size_t)v * 64 + lane;
    const float* dcb = CL + (size_t)h * 49 * 64 + (size_t)dvec * 64 + lane;
    float* cib = CI + (size_t)h * 44 * 64 + (size_t)v * 64 + lane;
    const size_t sCL = (size_t)H_ * 49 * 64;
    const size_t sCI = (size_t)H_ * 44 * 64;
    #pragma unroll 8
    for (int c = 0; c < NC_; ++c) {
        cib[(size_t)c * sCI] = x;
        float cl = clb[(size_t)c * sCL];
        float d  = dcb[(size_t)c * sCL];
        x = fmaf(d, x, cl);
    }
}

// ---- scan phase 3: re-scan with carry-in, emit attn (fp16 hi/lo, S x 512) ----
__global__ __launch_bounds__(64) void scan_p3(const float* __restrict__ Y1, const float* __restrict__ OC,
                                              const int* __restrict__ term, const float* __restrict__ CI,
                                              u16* __restrict__ attnH, u16* __restrict__ attnL) {
    const int b = blockIdx.x, c = b / H_, h = b % H_, lane = threadIdx.x;
    float kc[R_][ETA_], vc[R_], sc[ETA_];
    const float* ci = CI + (size_t)b * 44 * 64;
    #pragma unroll
    for (int r = 0; r < R_; ++r)
        #pragma unroll
        for (int e = 0; e < ETA_; ++e) kc[r][e] = ci[(r * 4 + e) * 64 + lane];
    #pragma unroll
    for (int r = 0; r < R_; ++r) vc[r] = ci[(32 + r) * 64 + lane];
    #pragma unroll
    for (int e = 0; e < ETA_; ++e) sc[e] = ci[(40 + e) * 64 + lane];
    for (int t = c * LC_; t < c * LC_ + LC_; ++t) {
        const float* row = Y1 + (size_t)t * N1_;
        const float* bh = row + h * 320;
        float rk = bh[lane], rq = bh[64 + lane], vv = bh[128 + lane], sb = bh[192 + lane], sg = bh[256 + lane];
        const float* pp = row + NKQV_ + h * 12;
        float nt = 1.f - (float)term[t];
        float vals = vv * sb, dbv = (1.f - sb) * nt;
        float occ[R_];
        #pragma unroll
        for (int r = 0; r < R_; ++r) occ[r] = OC[t * R_ + r];
        float qe[ETA_];
        #pragma unroll
        for (int e = 0; e < ETA_; ++e) {
            float gam = sg * pp[8 + e];
            float kg = rk * pp[e] * gam;
            float dgv = (1.f - gam) * nt;
            qe[e] = rq * pp[4 + e];
            sc[e] = dgv * sc[e] + kg;
            #pragma unroll
            for (int r = 0; r < R_; ++r) kc[r][e] = dgv * kc[r][e] + kg * occ[r];
        }
        #pragma unroll
        for (int r = 0; r < R_; ++r) vc[r] = dbv * vc[r] + vals * occ[r];
        float kdq[R_], nrm = 0.f;
        #pragma unroll
        for (int r = 0; r < R_; ++r) {
            float s = 0.f;
            #pragma unroll
            for (int e = 0; e < ETA_; ++e) s += kc[r][e] * qe[e];
            kdq[r] = s;
        }
        #pragma unroll
        for (int e = 0; e < ETA_; ++e) nrm += sc[e] * qe[e];
        #pragma unroll
        for (int m = 1; m < 64; m <<= 1) {
            #pragma unroll
            for (int r = 0; r < R_; ++r) kdq[r] += __shfl_xor(kdq[r], m);
            nrm += __shfl_xor(nrm, m);
        }
        float kv = 0.f;
        #pragma unroll
        for (int r = 0; r < R_; ++r) kv += vc[r] * kdq[r];
        float at = kv / (2.f * R_ * nrm + 1e-5f);
        size_t oi = (size_t)t * (H_ * DH_) + h * DH_ + lane;
        u16 hi = f2h(at);
        attnH[oi] = hi;
        attnL[oi] = f2h(at - h2f(hi));
    }
}

extern "C" void kernel_launch(void* const* d_in, const int* in_sizes, int n_in,
                              void* d_out, int out_size, void* d_ws, size_t ws_size,
                              hipStream_t stream) {
    const float* inputs = (const float*)d_in[0];
    const int*   term   = (const int*)d_in[1];
    const float* Wk     = (const float*)d_in[2];
    const float* bk     = (const float*)d_in[3];
    const float* Wp     = (const float*)d_in[4];
    const float* bp     = (const float*)d_in[5];
    const float* Wproj  = (const float*)d_in[6];
    const float* bproj  = (const float*)d_in[7];
    const float* TK     = (const float*)d_in[8];
    const float* TV     = (const float*)d_in[9];
    const float* SP     = (const float*)d_in[10];
    const float* tick   = (const float*)d_in[11];
    float* out = (float*)d_out;

    char* w = (char*)d_ws;
    u16* AbfH   = (u16*)w;  w += (size_t)S_ * D_ * 2;          // 8 MB
    u16* AbfL   = (u16*)w;  w += (size_t)S_ * D_ * 2;          // 8 MB
    u16* BTh    = (u16*)w;  w += (size_t)N1_ * D_ * 2;         // 5.5 MB  [n][k]
    u16* WpTh   = (u16*)w;  w += (size_t)D_ * 512 * 2;         // 1 MB    [n][k]
    u16* attnH  = (u16*)w;  w += (size_t)S_ * 512 * 2;         // 4 MB
    u16* attnL  = (u16*)w;  w += (size_t)S_ * 512 * 2;         // 4 MB
    float* biasb = (float*)w; w += (size_t)N1_ * 4;
    float* Y1   = (float*)w; w += (size_t)S_ * N1_ * 4;        // 44 MB
    float* OC   = (float*)w; w += (size_t)S_ * R_ * 4;
    float* CL   = (float*)w; w += (size_t)NC_ * H_ * 49 * 64 * 4;  // 25.7 MB
    float* CI   = (float*)w; w += (size_t)NC_ * H_ * 44 * 64 * 4;  // 23.1 MB

    prep_all<<<PB_TOTAL, 256, 0, stream>>>(inputs, Wk, Wp, Wproj, bk, bp, tick,
                                           AbfH, AbfL, BTh, WpTh, biasb, OC);
    gemm_x2_pipe<<<dim3(N1_ / 128, S_ / 128), 256, 0, stream>>>(AbfH, AbfL, BTh, biasb, Y1, N1_, D_, 1);
    scan_p1<<<NC_ * H_, 64, 0, stream>>>(Y1, OC, term, CL);
    scan_comb<<<(H_ * 44 * 64) / 64, 64, 0, stream>>>(CL, CI, TK, TV, SP);
    scan_p3<<<NC_ * H_, 64, 0, stream>>>(Y1, OC, term, CI, attnH, attnL);
    gemm_x2_pipe<<<dim3(1024 / 128, S_ / 128), 256, 0, stream>>>(attnH, attnL, WpTh, bproj, out, D_, 512, 0);
}